// Round 1
// 775.161 us; speedup vs baseline: 1.1069x; 1.1069x over previous
//
#include <hip/hip_runtime.h>
#include <hip/hip_bf16.h>
#include <cstdint>

// Conformer block, MI355X gfx950. f32 inputs, f32 output, bf16 MFMA internals.
// B=8 N=1024 D=512 H=8 DH=64 FF=2048 CI=1024 K=31 MPE=512.
// Round 10: fused attention kernel (S rows in registers, exact softmax,
// P staged in LDS, PV partial-reduced in LDS) replaces S-gemm + softmax + PV.

using bf16_t = __hip_bfloat16;
typedef __bf16 bf16x8 __attribute__((ext_vector_type(8)));
typedef float floatx4 __attribute__((ext_vector_type(4)));

struct alignas(16) hbf8 { bf16_t h[8]; };
struct alignas(8)  hbf4 { bf16_t h[4]; };

__device__ __forceinline__ float  b2f(bf16_t h) { return __bfloat162float(h); }
__device__ __forceinline__ bf16_t f2b(float f)  { return __float2bfloat16(f); }
__device__ __forceinline__ float  sig_(float x) { return 1.f / (1.f + __expf(-x)); }

// async global->LDS, 16B/lane; LDS dest must be wave-uniform base + lane*16 (m97 pattern)
__device__ __forceinline__ void async16(const void* g, void* l) {
  __builtin_amdgcn_global_load_lds(
      (const __attribute__((address_space(1))) unsigned int*)(uintptr_t)g,
      (__attribute__((address_space(3))) unsigned int*)(uintptr_t)l, 16, 0, 0);
}

// ---------------------------------------------------------------- GEMM (MFMA)
// C[M,N] = A[M,K] @ Bt[N,K]^T   (bf16 operands, k-contiguous, f32 accum)
// z = blockIdx.z = zb*8+zh (batch, head)
// EPI 0: C_bf16 = alpha*acc + bias     EPI 1: C_bf16 = swish(acc + bias)
// EPI 2: resid_f32 += beta*(acc+bias)  EPI 3: C_bf16 = acc + qr gather (unused now)
struct GemmArgs {
  const bf16_t* A; const bf16_t* Bt; const float* bias; const bf16_t* qr;
  bf16_t* C; float* resid;
  int K, lda, ldb, ldc, ldqr;
  long sAb, sAh, sBb, sBh, sCb, sCh;
  float alpha, beta;
};

template <int BM, int BN, int WR, int WC, int EPI>
__global__ __launch_bounds__(256) void gemm_bt(GemmArgs g) {
  constexpr int FM = BM / (WR * 16);
  constexpr int FN = BN / (WC * 16);
  constexpr int IA = (BM * 4) / 256;
  constexpr int IB = (BN * 4) / 256;
  __shared__ __align__(16) bf16_t As[BM * 32];
  __shared__ __align__(16) bf16_t Bs[BN * 32];
  const int tid = threadIdx.x;
  const int lane = tid & 63, w = tid >> 6;
  const int bm0 = blockIdx.y * BM, bn0 = blockIdx.x * BN;
  const int zb = blockIdx.z >> 3, zh = blockIdx.z & 7;
  const bf16_t* Ab = g.A + (long)zb * g.sAb + (long)zh * g.sAh;
  const bf16_t* Bb = g.Bt + (long)zb * g.sBb + (long)zh * g.sBh;
  const int wm0 = (w / WC) * (FM * 16);
  const int wn0 = (w % WC) * (FN * 16);
  const int lrow = lane & 15, lq = lane >> 4;

  floatx4 acc[FM][FN] = {};

  for (int k0 = 0; k0 < g.K; k0 += 32) {
#pragma unroll
    for (int i = 0; i < IA; ++i) {
      int c = i * 256 + tid;
      int m = c >> 2, kk = (c & 3) * 8;
      async16(Ab + (long)(bm0 + m) * g.lda + (k0 + kk), (char*)As + c * 16);
    }
#pragma unroll
    for (int i = 0; i < IB; ++i) {
      int c = i * 256 + tid;
      int n = bn0 + (c >> 2), kk = (c & 3) * 8;
      async16(Bb + (long)n * g.ldb + (k0 + kk), (char*)Bs + c * 16);
    }
    __syncthreads();   // drains vmcnt before s_barrier (compiler-inserted)
    bf16x8 af[FM], bfr[FN];
#pragma unroll
    for (int fm = 0; fm < FM; ++fm)
      af[fm] = *(const bf16x8*)(As + (wm0 + fm * 16 + lrow) * 32 + lq * 8);
#pragma unroll
    for (int fn = 0; fn < FN; ++fn)
      bfr[fn] = *(const bf16x8*)(Bs + (wn0 + fn * 16 + lrow) * 32 + lq * 8);
#pragma unroll
    for (int fm = 0; fm < FM; ++fm)
#pragma unroll
      for (int fn = 0; fn < FN; ++fn)
        acc[fm][fn] = __builtin_amdgcn_mfma_f32_16x16x32_bf16(af[fm], bfr[fn], acc[fm][fn], 0, 0, 0);
    __syncthreads();
  }

  const int bi = bm0 + wm0 + lq * 4;    // + fm*16 + r
  const int bj = bn0 + wn0 + lrow;      // + fn*16
  if constexpr (EPI == 2) {
    float* R = g.resid;
#pragma unroll
    for (int fm = 0; fm < FM; ++fm)
#pragma unroll
      for (int fn = 0; fn < FN; ++fn) {
        int j = bj + fn * 16;
        float bv = g.bias ? g.bias[j] : 0.f;
#pragma unroll
        for (int r = 0; r < 4; ++r) {
          long i = bi + fm * 16 + r;
          R[i * g.ldc + j] += g.beta * (acc[fm][fn][r] + bv);
        }
      }
  } else {
    bf16_t* C = g.C + (long)zb * g.sCb + (long)zh * g.sCh;
#pragma unroll
    for (int fm = 0; fm < FM; ++fm)
#pragma unroll
      for (int fn = 0; fn < FN; ++fn) {
        int j = bj + fn * 16;
        float bv = (EPI != 3 && g.bias) ? g.bias[j] : 0.f;
#pragma unroll
        for (int r = 0; r < 4; ++r) {
          int i = bi + fm * 16 + r;
          float v = acc[fm][fn][r];
          if constexpr (EPI == 0) v = g.alpha * v + bv;
          if constexpr (EPI == 1) { v += bv; v = v * sig_(v); }
          if constexpr (EPI == 3) {
            int t = i - j; t = t < -512 ? -512 : (t > 512 ? 512 : t);
            v += b2f(g.qr[(long)((zb * 1024 + i) * 8 + zh) * g.ldqr + (t + 512)]);
          }
          C[(long)i * g.ldc + j] = f2b(v);
        }
      }
  }
}

// ---------------------------------------------------------------- fused attention
// One block = one (z = b*8+h, 32-row i-tile). 512 threads = 8 waves.
// Wave w owns j-slab [w*128, w*128+128). S rows held in registers (f32),
// exact softmax (shfl within 16-lane groups + LDS cross-wave), P -> LDS bf16
// (XOR-swizzled), PV via MFMA with VT global B-operand, K-split partials
// reduced through the same LDS (re-aliased after a barrier).
// Q: bf16 [(b*1024+i)*512 + h*64 + d] (pre-scaled by 1/8)
// KV: bf16 [(b*1024+j)*1024 + h*64 + d] (K half)
// VT: bf16 [(b*8+h)*65536 + d*1024 + j]
// QR: bf16 [((bl*1024+i)*8+h)*1152 + t], bl chunk-local batch
// O: bf16 [(b*1024+i)*512 + h*64 + d]
__global__ __launch_bounds__(512) void attn_kernel(
    const bf16_t* __restrict__ Q, const bf16_t* __restrict__ KV,
    const bf16_t* __restrict__ VT, const bf16_t* __restrict__ QR,
    bf16_t* __restrict__ O, int b0) {
  __shared__ __align__(16) bf16_t Pls[32 * 1024];   // 64 KB; aliased: scratch -> P -> partials
  float* scr = (float*)Pls;  // [0,288) rmax red, [288,320) row max, [320,608) sum red, [608,640) inv

  const int tid = threadIdx.x;
  const int w = tid >> 6, lane = tid & 63;
  const int lrow = lane & 15, lq = lane >> 4;
  const int i0 = blockIdx.x * 32;
  const int zl = blockIdx.y;                 // chunk-local z
  const int zbl = zl >> 3, zh = zl & 7;
  const int b = b0 + zbl;
  const int j0w = w * 128;

  const bf16_t* Qb  = Q  + ((long)(b * 1024 + i0)) * 512 + zh * 64;
  const bf16_t* Kb  = KV + ((long)b * 1024) * 1024 + zh * 64;
  const bf16_t* VTb = VT + ((long)(b * 8 + zh)) * 65536;

  // ---- phase 1: S = Q K^T + bias (f32 in regs) ----
  bf16x8 af[2][2];
#pragma unroll
  for (int fm = 0; fm < 2; ++fm)
#pragma unroll
    for (int ks = 0; ks < 2; ++ks)
      af[fm][ks] = *(const bf16x8*)(Qb + (long)(fm * 16 + lrow) * 512 + ks * 32 + lq * 8);

  floatx4 sacc[2][8] = {};
#pragma unroll
  for (int fn = 0; fn < 8; ++fn) {
#pragma unroll
    for (int ks = 0; ks < 2; ++ks) {
      bf16x8 bk = *(const bf16x8*)(Kb + (long)(j0w + fn * 16 + lrow) * 1024 + ks * 32 + lq * 8);
      sacc[0][fn] = __builtin_amdgcn_mfma_f32_16x16x32_bf16(af[0][ks], bk, sacc[0][fn], 0, 0, 0);
      sacc[1][fn] = __builtin_amdgcn_mfma_f32_16x16x32_bf16(af[1][ks], bk, sacc[1][fn], 0, 0, 0);
    }
  }

  // rel-pos bias gather (same addressing as old EPI 3)
#pragma unroll
  for (int fm = 0; fm < 2; ++fm)
#pragma unroll
    for (int r = 0; r < 4; ++r) {
      const int i = i0 + fm * 16 + lq * 4 + r;
      const bf16_t* qrow = QR + (long)((zbl * 1024 + i) * 8 + zh) * 1152 + 512;
      const int tb = i - j0w - lrow;
#pragma unroll
      for (int fn = 0; fn < 8; ++fn) {
        int t = tb - fn * 16;
        t = t < -512 ? -512 : (t > 512 ? 512 : t);
        sacc[fm][fn][r] += b2f(qrow[t]);
      }
    }

  // ---- exact softmax over full row (1024) ----
  float rmax[2][4];
#pragma unroll
  for (int fm = 0; fm < 2; ++fm)
#pragma unroll
    for (int r = 0; r < 4; ++r) {
      float m = sacc[fm][0][r];
#pragma unroll
      for (int fn = 1; fn < 8; ++fn) m = fmaxf(m, sacc[fm][fn][r]);
      rmax[fm][r] = m;
    }
#pragma unroll
  for (int off = 1; off < 16; off <<= 1)
#pragma unroll
    for (int fm = 0; fm < 2; ++fm)
#pragma unroll
      for (int r = 0; r < 4; ++r)
        rmax[fm][r] = fmaxf(rmax[fm][r], __shfl_xor(rmax[fm][r], off));
  if (lrow == 0)
#pragma unroll
    for (int fm = 0; fm < 2; ++fm)
#pragma unroll
      for (int r = 0; r < 4; ++r)
        scr[(fm * 16 + lq * 4 + r) * 9 + w] = rmax[fm][r];
  __syncthreads();
  if (tid < 32) {
    const float* rr = scr + tid * 9;
    float m = rr[0];
#pragma unroll
    for (int ww = 1; ww < 8; ++ww) m = fmaxf(m, rr[ww]);
    scr[288 + tid] = m;
  }
  __syncthreads();

  float rsum[2][4];
#pragma unroll
  for (int fm = 0; fm < 2; ++fm)
#pragma unroll
    for (int r = 0; r < 4; ++r) {
      const float m = scr[288 + fm * 16 + lq * 4 + r];
      float s = 0.f;
#pragma unroll
      for (int fn = 0; fn < 8; ++fn) {
        float e = __expf(sacc[fm][fn][r] - m);
        sacc[fm][fn][r] = e;
        s += e;
      }
      rsum[fm][r] = s;
    }
#pragma unroll
  for (int off = 1; off < 16; off <<= 1)
#pragma unroll
    for (int fm = 0; fm < 2; ++fm)
#pragma unroll
      for (int r = 0; r < 4; ++r)
        rsum[fm][r] += __shfl_xor(rsum[fm][r], off);
  if (lrow == 0)
#pragma unroll
    for (int fm = 0; fm < 2; ++fm)
#pragma unroll
      for (int r = 0; r < 4; ++r)
        scr[320 + (fm * 16 + lq * 4 + r) * 9 + w] = rsum[fm][r];
  __syncthreads();
  if (tid < 32) {
    const float* rr = scr + 320 + tid * 9;
    float s = rr[0];
#pragma unroll
    for (int ww = 1; ww < 8; ++ww) s += rr[ww];
    scr[608 + tid] = 1.f / s;
  }
  __syncthreads();
  float inv[2][4];
#pragma unroll
  for (int fm = 0; fm < 2; ++fm)
#pragma unroll
    for (int r = 0; r < 4; ++r)
      inv[fm][r] = scr[608 + fm * 16 + lq * 4 + r];
  __syncthreads();   // scratch reads done before any P write clobbers it

  // ---- P -> LDS (bf16, XOR swizzle ^((i&7)<<4); each wave writes only its slab) ----
#pragma unroll
  for (int fm = 0; fm < 2; ++fm)
#pragma unroll
    for (int fn = 0; fn < 8; ++fn)
#pragma unroll
      for (int r = 0; r < 4; ++r) {
        const int i = fm * 16 + lq * 4 + r;
        const int j = j0w + fn * 16 + lrow;
        const unsigned boff = (unsigned)(i * 2048 + j * 2) ^ ((unsigned)(i & 7) << 4);
        *(bf16_t*)((char*)Pls + boff) = f2b(sacc[fm][fn][r] * inv[fm][r]);
      }
  // no barrier needed: each wave reads back only its own slab

  // ---- phase 2: O partials = P_slab @ V_slab ----
  floatx4 oacc[2][4] = {};
#pragma unroll
  for (int ks = 0; ks < 4; ++ks) {
    const int j = j0w + ks * 32;
    bf16x8 ap[2];
#pragma unroll
    for (int fm = 0; fm < 2; ++fm) {
      const int i = fm * 16 + lrow;
      const unsigned boff = (unsigned)(i * 2048 + (j + lq * 8) * 2) ^ ((unsigned)(i & 7) << 4);
      ap[fm] = *(const bf16x8*)((char*)Pls + boff);
    }
#pragma unroll
    for (int fd = 0; fd < 4; ++fd) {
      bf16x8 bv = *(const bf16x8*)(VTb + (long)(fd * 16 + lrow) * 1024 + j + lq * 8);
      oacc[0][fd] = __builtin_amdgcn_mfma_f32_16x16x32_bf16(ap[0], bv, oacc[0][fd], 0, 0, 0);
      oacc[1][fd] = __builtin_amdgcn_mfma_f32_16x16x32_bf16(ap[1], bv, oacc[1][fd], 0, 0, 0);
    }
  }
  __syncthreads();   // all PV reads of P done -> safe to overwrite with partials

  // partials: per-wave f32 [i][64] at float offset w*2048 (re-aliases Pls)
  {
    float* part = (float*)Pls + w * 2048;
#pragma unroll
    for (int fm = 0; fm < 2; ++fm)
#pragma unroll
      for (int fd = 0; fd < 4; ++fd)
#pragma unroll
        for (int r = 0; r < 4; ++r)
          part[(fm * 16 + lq * 4 + r) * 64 + fd * 16 + lrow] = oacc[fm][fd][r];
  }
  __syncthreads();

  // K-reduce 8 partials, write O
  {
    const int i = tid >> 4;
    const int d0 = (tid & 15) * 4;
    floatx4 s = {};
#pragma unroll
    for (int ww = 0; ww < 8; ++ww)
      s += *(const floatx4*)((const float*)Pls + ww * 2048 + i * 64 + d0);
    hbf4 o4;
#pragma unroll
    for (int m = 0; m < 4; ++m) o4.h[m] = f2b(s[m]);
    *(hbf4*)(O + (long)(b * 1024 + i0 + i) * 512 + zh * 64 + d0) = o4;
  }
}

// ---------------------------------------------------------------- glue kernels
__global__ __launch_bounds__(256) void diag_kernel(float* __restrict__ out, long n, float v) {
  long i = (long)blockIdx.x * 256 + threadIdx.x;
  if (i < n) out[i] = v;
}

__global__ __launch_bounds__(256) void copy_kernel(const float* __restrict__ x, float* __restrict__ X) {
  long idx = ((long)blockIdx.x * 256 + threadIdx.x) * 4;
  *(float4*)(X + idx) = *(const float4*)(x + idx);
}

// pad rel [1025,64] f32 -> RELP [1152,64] bf16 (zero tail)
__global__ __launch_bounds__(256) void relpad_kernel(const float* __restrict__ rel, bf16_t* __restrict__ RELP) {
  int i = blockIdx.x * 256 + threadIdx.x;
  if (i < 73728) {
    int r = i >> 6, c = i & 63;
    RELP[i] = (r < 1025) ? f2b(rel[r * 64 + c]) : f2b(0.f);
  }
}

template <bool F32OUT>
__global__ __launch_bounds__(256) void ln_kernel(const float* __restrict__ X, const float* __restrict__ gam,
                                                 const float* __restrict__ bet, void* __restrict__ outv) {
  int row = blockIdx.x, tid = threadIdx.x;
  const float* x = X + (long)row * 512;
  float a = x[tid], b = x[tid + 256];
  float s = a + b, q = a * a + b * b;
  for (int off = 32; off; off >>= 1) { s += __shfl_down(s, off); q += __shfl_down(q, off); }
  __shared__ float red[8];
  int w = tid >> 6;
  if ((tid & 63) == 0) { red[w] = s; red[w + 4] = q; }
  __syncthreads();
  float ts = red[0] + red[1] + red[2] + red[3];
  float tq = red[4] + red[5] + red[6] + red[7];
  float mean = ts * (1.f / 512.f);
  float var = tq * (1.f / 512.f) - mean * mean;
  float rs = rsqrtf(var + 1e-5f);
  float o0 = (a - mean) * rs * gam[tid]       + bet[tid];
  float o1 = (b - mean) * rs * gam[tid + 256] + bet[tid + 256];
  if constexpr (F32OUT) {
    float* out = (float*)outv;
    out[(long)row * 512 + tid]       = o0;
    out[(long)row * 512 + tid + 256] = o1;
  } else {
    bf16_t* out = (bf16_t*)outv;
    out[(long)row * 512 + tid]       = f2b(o0);
    out[(long)row * 512 + tid + 256] = f2b(o1);
  }
}

__global__ __launch_bounds__(256) void transpose_kernel(const float* __restrict__ in, bf16_t* __restrict__ out,
                                                        int R, int C) {
  __shared__ float t[32][33];
  int c0 = blockIdx.x * 32, r0 = blockIdx.y * 32;
  int tx = threadIdx.x & 31, ty = threadIdx.x >> 5;
#pragma unroll
  for (int i = 0; i < 4; ++i)
    t[ty + i * 8][tx] = in[(long)(r0 + ty + i * 8) * C + c0 + tx];
  __syncthreads();
#pragma unroll
  for (int i = 0; i < 4; ++i)
    out[(long)(c0 + ty + i * 8) * R + r0 + tx] = f2b(t[tx][ty + i * 8]);
}

// VT[z=b*8+h][d][j] = KV[(b*1024+j)*1024 + 512 + h*64 + d]
__global__ __launch_bounds__(256) void vt_kernel(const bf16_t* __restrict__ KV, bf16_t* __restrict__ VT) {
  int jb = blockIdx.x, z = blockIdx.y;
  int b = z >> 3, h = z & 7;
  const bf16_t* src = KV + (long)b * 1024 * 1024 + 512 + h * 64;
  bf16_t* dst = VT + (long)z * 65536;
  __shared__ bf16_t t[64][65];
  int tid = threadIdx.x;
#pragma unroll
  for (int i = 0; i < 16; ++i) {
    int l = i * 256 + tid;
    int j = l >> 6, d = l & 63;
    t[d][j] = src[(long)(jb * 64 + j) * 1024 + d];
  }
  __syncthreads();
#pragma unroll
  for (int i = 0; i < 16; ++i) {
    int l = i * 256 + tid;
    int d = l >> 6, j = l & 63;
    dst[(long)d * 1024 + jb * 64 + j] = t[d][j];
  }
}

__global__ __launch_bounds__(256) void glu_kernel(const bf16_t* __restrict__ P, bf16_t* __restrict__ out) {
  long idx = ((long)blockIdx.x * 256 + threadIdx.x) * 8;
  long r = idx >> 10;
  int c = (int)(idx & 1023);
  hbf8 a = *(const hbf8*)(P + r * 2048 + c);
  hbf8 g = *(const hbf8*)(P + r * 2048 + 1024 + c);
  hbf8 o;
#pragma unroll
  for (int i = 0; i < 8; ++i) o.h[i] = f2b(b2f(a.h[i]) * sig_(b2f(g.h[i])));
  *(hbf8*)(out + idx) = o;
}

__global__ __launch_bounds__(256) void dwconv_kernel(const bf16_t* __restrict__ G, const float* __restrict__ dw,
    const float* __restrict__ db, const float* __restrict__ bng, const float* __restrict__ bnb,
    const float* __restrict__ bnm, const float* __restrict__ bnv, bf16_t* __restrict__ out) {
  int n0 = blockIdx.x * 32, c0 = blockIdx.y * 64, b = blockIdx.z;
  __shared__ bf16_t t[62][64];
  __shared__ float dws[31][64];
  int tid = threadIdx.x;
  const bf16_t* src = G + (long)b * 1024 * 1024 + c0;
#pragma unroll
  for (int i = 0; i < 16; ++i) {
    int l = i * 256 + tid;
    if (l < 3968) {
      int rr = l >> 6, c = l & 63;
      int n = n0 - 15 + rr;
      t[rr][c] = (n >= 0 && n < 1024) ? src[(long)n * 1024 + c] : f2b(0.f);
    }
  }
#pragma unroll
  for (int i = 0; i < 8; ++i) {
    int l = i * 256 + tid;
    if (l < 1984) {
      int k = l >> 6, c = l & 63;
      dws[k][c] = dw[(long)(c0 + c) * 31 + k];
    }
  }
  __syncthreads();
  int c = tid & 63, nl = tid >> 6;
  float rs = rsqrtf(bnv[c0 + c] + 1e-5f);
  float sc = rs * bng[c0 + c];
  float ab = (db[c0 + c] - bnm[c0 + c]) * sc + bnb[c0 + c];
#pragma unroll
  for (int j = 0; j < 8; ++j) {
    int rr = nl * 8 + j;
    float s = 0.f;
#pragma unroll
    for (int k = 0; k < 31; ++k) s += b2f(t[rr + k][c]) * dws[k][c];
    float y = s * sc + ab;
    out[((long)b * 1024 + n0 + rr) * 1024 + c0 + c] = f2b(y * sig_(y));
  }
}

// ---------------------------------------------------------------- launch
extern "C" void kernel_launch(void* const* d_in, const int* in_sizes, int n_in,
                              void* d_out, int out_size, void* d_ws, size_t ws_size,
                              hipStream_t stream) {
  auto fail = [&](float code) {
    diag_kernel<<<(out_size + 255) / 256, 256, 0, stream>>>((float*)d_out, out_size, code);
  };
  if (n_in != 34)             { fail(70.f);  return; }
  if (in_sizes[0] != 4194304) { fail(80.f);  return; }

  const float* x     = (const float*)d_in[0];
  const float* f1_g  = (const float*)d_in[1];
  const float* f1_b  = (const float*)d_in[2];
  const float* f1_w1 = (const float*)d_in[3];
  const float* f1_b1 = (const float*)d_in[4];
  const float* f1_w2 = (const float*)d_in[5];
  const float* f1_b2 = (const float*)d_in[6];
  const float* a_g   = (const float*)d_in[7];
  const float* a_b   = (const float*)d_in[8];
  const float* wq    = (const float*)d_in[9];
  const float* wkv   = (const float*)d_in[10];
  const float* wo    = (const float*)d_in[11];
  const float* wo_b  = (const float*)d_in[12];
  const float* rel   = (const float*)d_in[13];
  const float* c_g   = (const float*)d_in[14];
  const float* c_b   = (const float*)d_in[15];
  const float* cw1   = (const float*)d_in[16];
  const float* cb1   = (const float*)d_in[17];
  const float* dwp   = (const float*)d_in[18];
  const float* dbp   = (const float*)d_in[19];
  const float* bn_g  = (const float*)d_in[20];
  const float* bn_b  = (const float*)d_in[21];
  const float* bn_m  = (const float*)d_in[22];
  const float* bn_v  = (const float*)d_in[23];
  const float* cw2   = (const float*)d_in[24];
  const float* cb2   = (const float*)d_in[25];
  const float* f2_g  = (const float*)d_in[26];
  const float* f2_b  = (const float*)d_in[27];
  const float* f2_w1 = (const float*)d_in[28];
  const float* f2_b1 = (const float*)d_in[29];
  const float* f2_w2 = (const float*)d_in[30];
  const float* f2_b2 = (const float*)d_in[31];
  const float* p_g   = (const float*)d_in[32];
  const float* p_b   = (const float*)d_in[33];

  // ---- workspace arena ----
  // X 16.78M | WT 13.63M | D 33.55M {Q,KV,VT}/{GLU,DWO} | E: max(MID 33.55M, QR NB*18.87M)
  // | RELP after max(...)
  char* ws = (char*)d_ws;
  const size_t OFF_X  = 0;
  const size_t OFF_WT = 16777216;
  const size_t OFF_D  = 30408704;
  const size_t OFF_E  = 63963136;
  // chunk size: largest NB whose QR fits alongside the rest (S no longer materialized)
  int NB = 1;
  {
    const int cands[4] = {8, 4, 2, 1};
    for (int ci = 0; ci < 4; ++ci) {
      int nb = cands[ci];
      unsigned long long attn = (unsigned long long)nb * 18874368ULL;
      unsigned long long emax = attn > 33554432ULL ? attn : 33554432ULL;
      if (ws_size >= OFF_E + emax + 147456ULL) { NB = nb; break; }
    }
  }
  size_t relp_off;
  {
    unsigned long long attn = (unsigned long long)NB * 18874368ULL;
    unsigned long long emax = attn > 33554432ULL ? attn : 33554432ULL;
    if (ws_size < OFF_E + emax + 147456ULL) { fail(200.f); return; }
    relp_off = OFF_E + (size_t)emax;
  }

  float*  X   = (float*)(ws + OFF_X);
  bf16_t* WT  = (bf16_t*)(ws + OFF_WT);
  bf16_t* Q   = (bf16_t*)(ws + OFF_D);
  bf16_t* KV  = (bf16_t*)(ws + OFF_D + 8388608);
  bf16_t* VT  = (bf16_t*)(ws + OFF_D + 25165824);
  bf16_t* GLU = (bf16_t*)(ws + OFF_D);
  bf16_t* DWO = (bf16_t*)(ws + OFF_D + 16777216);
  bf16_t* MID = (bf16_t*)(ws + OFF_E);
  bf16_t* QR  = (bf16_t*)(ws + OFF_E);                              // chunk-local
  bf16_t* RELP= (bf16_t*)(ws + relp_off);
  bf16_t* H   = (bf16_t*)d_out;   // bf16 scratch inside f32 out buffer
  bf16_t* O   = (bf16_t*)d_out;   // final f32 LN overwrites at the end

  bf16_t* f1_w1t = WT;            bf16_t* f1_w2t = WT + 1048576;
  bf16_t* wqt    = WT + 2097152;  bf16_t* wkvt   = WT + 2359296;
  bf16_t* wot    = WT + 2883584;  bf16_t* cw1t   = WT + 3145728;
  bf16_t* cw2t   = WT + 4194304;  bf16_t* f2_w1t = WT + 4718592;
  bf16_t* f2_w2t = WT + 5767168;

  auto GA = [](const bf16_t* A, const bf16_t* Bt, const float* bias, bf16_t* C,
               float* resid, const bf16_t* qr, int K, int lda, int ldb, int ldc,
               float alpha, float beta) {
    GemmArgs g{}; g.A = A; g.Bt = Bt; g.bias = bias; g.qr = qr; g.C = C; g.resid = resid;
    g.K = K; g.lda = lda; g.ldb = ldb; g.ldc = ldc; g.ldqr = 1152;
    g.sAb = g.sAh = g.sBb = g.sBh = g.sCb = g.sCh = 0; g.alpha = alpha; g.beta = beta;
    return g;
  };
  auto T = [&](const float* in, bf16_t* out, int R, int C) {
    transpose_kernel<<<dim3(C / 32, R / 32), 256, 0, stream>>>(in, out, R, C);
  };

  copy_kernel<<<4096, 256, 0, stream>>>(x, X);
  relpad_kernel<<<288, 256, 0, stream>>>(rel, RELP);
  T(f1_w1, f1_w1t, 512, 2048);  T(f1_w2, f1_w2t, 2048, 512);
  T(wq, wqt, 512, 512);         T(wkv, wkvt, 512, 1024);
  T(wo, wot, 512, 512);         T(cw1, cw1t, 512, 2048);
  T(cw2, cw2t, 1024, 512);      T(f2_w1, f2_w1t, 512, 2048);
  T(f2_w2, f2_w2t, 2048, 512);

  // ---- FF1 half-step ----
  ln_kernel<false><<<8192, 256, 0, stream>>>(X, f1_g, f1_b, H);
  { GemmArgs g = GA(H, f1_w1t, f1_b1, MID, nullptr, nullptr, 512, 512, 512, 2048, 1.f, 0.f);
    gemm_bt<128, 128, 2, 2, 1><<<dim3(16, 64, 1), 256, 0, stream>>>(g); }
  { GemmArgs g = GA(MID, f1_w2t, f1_b2, nullptr, X, nullptr, 2048, 2048, 2048, 512, 1.f, 0.5f);
    gemm_bt<64, 128, 1, 4, 2><<<dim3(4, 128, 1), 256, 0, stream>>>(g); }

  // ---- attention ----
  ln_kernel<false><<<8192, 256, 0, stream>>>(X, a_g, a_b, H);
  { GemmArgs g = GA(H, wqt, nullptr, Q, nullptr, nullptr, 512, 512, 512, 512, 0.125f, 0.f);
    gemm_bt<128, 128, 2, 2, 0><<<dim3(4, 64, 1), 256, 0, stream>>>(g); }   // q (scale folded)
  { GemmArgs g = GA(H, wkvt, nullptr, KV, nullptr, nullptr, 512, 512, 512, 1024, 1.f, 0.f);
    gemm_bt<128, 128, 2, 2, 0><<<dim3(8, 64, 1), 256, 0, stream>>>(g); }   // k|v
  vt_kernel<<<dim3(16, 64), 256, 0, stream>>>(KV, VT);

  for (int b0 = 0; b0 < 8; b0 += NB) {
    const bf16_t* Qc = Q + (long)b0 * 524288;
    // qr = q @ RELP^T for whole chunk: Q viewed as [NB*8192, 64] flat rows
    { GemmArgs g = GA(Qc, RELP, nullptr, QR, nullptr, nullptr, 64, 64, 64, 1152, 1.f, 0.f);
      gemm_bt<128, 128, 2, 2, 0><<<dim3(9, NB * 64, 1), 256, 0, stream>>>(g); }
    // fused: S = qk^T + bias -> softmax -> O = P @ V  (no S materialization)
    attn_kernel<<<dim3(32, NB * 8), 512, 0, stream>>>(Q, KV, VT, QR, O, b0);
  }
  { GemmArgs g = GA(O, wot, wo_b, nullptr, X, nullptr, 512, 512, 512, 512, 1.f, 1.f);
    gemm_bt<64, 128, 1, 4, 2><<<dim3(4, 128, 1), 256, 0, stream>>>(g); }   // x += o@wo + b

  // ---- conv module ----
  ln_kernel<false><<<8192, 256, 0, stream>>>(X, c_g, c_b, H);
  { GemmArgs g = GA(H, cw1t, cb1, MID, nullptr, nullptr, 512, 512, 512, 2048, 1.f, 0.f);
    gemm_bt<128, 128, 2, 2, 0><<<dim3(16, 64, 1), 256, 0, stream>>>(g); }  // pw1 + bias
  glu_kernel<<<4096, 256, 0, stream>>>(MID, GLU);
  dwconv_kernel<<<dim3(32, 16, 8), 256, 0, stream>>>(GLU, dwp, dbp, bn_g, bn_b, bn_m, bn_v, DWO);
  { GemmArgs g = GA(DWO, cw2t, cb2, nullptr, X, nullptr, 1024, 1024, 1024, 512, 1.f, 1.f);
    gemm_bt<64, 128, 1, 4, 2><<<dim3(4, 128, 1), 256, 0, stream>>>(g); }   // x += h@cw2 + b

  // ---- FF2 half-step + post-LN (f32 out) ----
  ln_kernel<false><<<8192, 256, 0, stream>>>(X, f2_g, f2_b, H);
  { GemmArgs g = GA(H, f2_w1t, f2_b1, MID, nullptr, nullptr, 512, 512, 512, 2048, 1.f, 0.f);
    gemm_bt<128, 128, 2, 2, 1><<<dim3(16, 64, 1), 256, 0, stream>>>(g); }
  { GemmArgs g = GA(MID, f2_w2t, f2_b2, nullptr, X, nullptr, 2048, 2048, 2048, 512, 1.f, 0.5f);
    gemm_bt<64, 128, 1, 4, 2><<<dim3(4, 128, 1), 256, 0, stream>>>(g); }
  ln_kernel<true><<<8192, 256, 0, stream>>>(X, p_g, p_b, (float*)d_out);
}

// Round 2
// 690.980 us; speedup vs baseline: 1.2417x; 1.1218x over previous
//
#include <hip/hip_runtime.h>
#include <hip/hip_bf16.h>
#include <cstdint>

// Conformer block, MI355X gfx950. f32 inputs, f32 output, bf16 MFMA internals.
// B=8 N=1024 D=512 H=8 DH=64 FF=2048 CI=1024 K=31 MPE=512.
// Round 11: rel-pos bias computed in-kernel (T = Q_tile @ RELP^T into LDS,
// gathered from LDS) — QR tensor and its gemm eliminated.

using bf16_t = __hip_bfloat16;
typedef __bf16 bf16x8 __attribute__((ext_vector_type(8)));
typedef float floatx4 __attribute__((ext_vector_type(4)));

struct alignas(16) hbf8 { bf16_t h[8]; };
struct alignas(8)  hbf4 { bf16_t h[4]; };

__device__ __forceinline__ float  b2f(bf16_t h) { return __bfloat162float(h); }
__device__ __forceinline__ bf16_t f2b(float f)  { return __float2bfloat16(f); }
__device__ __forceinline__ float  sig_(float x) { return 1.f / (1.f + __expf(-x)); }

// async global->LDS, 16B/lane; LDS dest must be wave-uniform base + lane*16 (m97 pattern)
__device__ __forceinline__ void async16(const void* g, void* l) {
  __builtin_amdgcn_global_load_lds(
      (const __attribute__((address_space(1))) unsigned int*)(uintptr_t)g,
      (__attribute__((address_space(3))) unsigned int*)(uintptr_t)l, 16, 0, 0);
}

// ---------------------------------------------------------------- GEMM (MFMA)
// C[M,N] = A[M,K] @ Bt[N,K]^T   (bf16 operands, k-contiguous, f32 accum)
// z = blockIdx.z = zb*8+zh (batch, head)
// EPI 0: C_bf16 = alpha*acc + bias     EPI 1: C_bf16 = swish(acc + bias)
// EPI 2: resid_f32 += beta*(acc+bias)
struct GemmArgs {
  const bf16_t* A; const bf16_t* Bt; const float* bias; const bf16_t* qr;
  bf16_t* C; float* resid;
  int K, lda, ldb, ldc, ldqr;
  long sAb, sAh, sBb, sBh, sCb, sCh;
  float alpha, beta;
};

template <int BM, int BN, int WR, int WC, int EPI>
__global__ __launch_bounds__(256) void gemm_bt(GemmArgs g) {
  constexpr int FM = BM / (WR * 16);
  constexpr int FN = BN / (WC * 16);
  constexpr int IA = (BM * 4) / 256;
  constexpr int IB = (BN * 4) / 256;
  __shared__ __align__(16) bf16_t As[BM * 32];
  __shared__ __align__(16) bf16_t Bs[BN * 32];
  const int tid = threadIdx.x;
  const int lane = tid & 63, w = tid >> 6;
  const int bm0 = blockIdx.y * BM, bn0 = blockIdx.x * BN;
  const int zb = blockIdx.z >> 3, zh = blockIdx.z & 7;
  const bf16_t* Ab = g.A + (long)zb * g.sAb + (long)zh * g.sAh;
  const bf16_t* Bb = g.Bt + (long)zb * g.sBb + (long)zh * g.sBh;
  const int wm0 = (w / WC) * (FM * 16);
  const int wn0 = (w % WC) * (FN * 16);
  const int lrow = lane & 15, lq = lane >> 4;

  floatx4 acc[FM][FN] = {};

  for (int k0 = 0; k0 < g.K; k0 += 32) {
#pragma unroll
    for (int i = 0; i < IA; ++i) {
      int c = i * 256 + tid;
      int m = c >> 2, kk = (c & 3) * 8;
      async16(Ab + (long)(bm0 + m) * g.lda + (k0 + kk), (char*)As + c * 16);
    }
#pragma unroll
    for (int i = 0; i < IB; ++i) {
      int c = i * 256 + tid;
      int n = bn0 + (c >> 2), kk = (c & 3) * 8;
      async16(Bb + (long)n * g.ldb + (k0 + kk), (char*)Bs + c * 16);
    }
    __syncthreads();   // drains vmcnt before s_barrier (compiler-inserted)
    bf16x8 af[FM], bfr[FN];
#pragma unroll
    for (int fm = 0; fm < FM; ++fm)
      af[fm] = *(const bf16x8*)(As + (wm0 + fm * 16 + lrow) * 32 + lq * 8);
#pragma unroll
    for (int fn = 0; fn < FN; ++fn)
      bfr[fn] = *(const bf16x8*)(Bs + (wn0 + fn * 16 + lrow) * 32 + lq * 8);
#pragma unroll
    for (int fm = 0; fm < FM; ++fm)
#pragma unroll
      for (int fn = 0; fn < FN; ++fn)
        acc[fm][fn] = __builtin_amdgcn_mfma_f32_16x16x32_bf16(af[fm], bfr[fn], acc[fm][fn], 0, 0, 0);
    __syncthreads();
  }

  const int bi = bm0 + wm0 + lq * 4;    // + fm*16 + r
  const int bj = bn0 + wn0 + lrow;      // + fn*16
  if constexpr (EPI == 2) {
    float* R = g.resid;
#pragma unroll
    for (int fm = 0; fm < FM; ++fm)
#pragma unroll
      for (int fn = 0; fn < FN; ++fn) {
        int j = bj + fn * 16;
        float bv = g.bias ? g.bias[j] : 0.f;
#pragma unroll
        for (int r = 0; r < 4; ++r) {
          long i = bi + fm * 16 + r;
          R[i * g.ldc + j] += g.beta * (acc[fm][fn][r] + bv);
        }
      }
  } else {
    bf16_t* C = g.C + (long)zb * g.sCb + (long)zh * g.sCh;
#pragma unroll
    for (int fm = 0; fm < FM; ++fm)
#pragma unroll
      for (int fn = 0; fn < FN; ++fn) {
        int j = bj + fn * 16;
        float bv = g.bias ? g.bias[j] : 0.f;
#pragma unroll
        for (int r = 0; r < 4; ++r) {
          int i = bi + fm * 16 + r;
          float v = acc[fm][fn][r];
          if constexpr (EPI == 0) v = g.alpha * v + bv;
          if constexpr (EPI == 1) { v += bv; v = v * sig_(v); }
          C[(long)i * g.ldc + j] = f2b(v);
        }
      }
  }
}

// ---------------------------------------------------------------- fused attention
// One block = one (z = b*8+h, 32-row i-tile). 512 threads = 8 waves.
// Phase 0: T[i][u] = q_i . rel_u via MFMA into LDS (wave w owns u-slab
//          [w*144, w*144+144); RELP global is 144 KB, L2-resident).
// Phase 1: S = Q K^T (regs) + bias gathered from T in LDS.
// Phase 2: exact softmax (shfl within 16-lane groups + LDS cross-wave).
// Phase 3: P -> LDS bf16 (XOR-swizzled, aliases T), PV via MFMA with global
//          VT B-operand, per-wave K-split partials reduced through LDS.
// Q: bf16 [(b*1024+i)*512 + h*64 + d] (pre-scaled by 1/8)
// KV: bf16 [(b*1024+j)*1024 + h*64 + d] (K half)
// VT: bf16 [(b*8+h)*65536 + d*1024 + j]
// RELP: bf16 [1152][64] (rows >=1025 zero)
// O: bf16 [(b*1024+i)*512 + h*64 + d]
__global__ __launch_bounds__(512) void attn_kernel(
    const bf16_t* __restrict__ Q, const bf16_t* __restrict__ KV,
    const bf16_t* __restrict__ VT, const bf16_t* __restrict__ RELP,
    bf16_t* __restrict__ O) {
  constexpr int LDT = 1160;                         // elems; 2320 B row stride -> 4-bank rotate
  __shared__ __align__(16) bf16_t Tls[32 * LDT];    // 74240 B; aliased: T -> P -> partials
  __shared__ float scr[640];  // [0,288) rmax red, [288,320) row max, [320,608) sum red, [608,640) inv

  const int tid = threadIdx.x;
  const int w = tid >> 6, lane = tid & 63;
  const int lrow = lane & 15, lq = lane >> 4;
  const int i0 = blockIdx.x * 32;
  const int z = blockIdx.y;
  const int b = z >> 3, zh = z & 7;
  const int j0w = w * 128;

  const bf16_t* Qb  = Q  + ((long)(b * 1024 + i0)) * 512 + zh * 64;
  const bf16_t* Kb  = KV + ((long)b * 1024) * 1024 + zh * 64;
  const bf16_t* VTb = VT + ((long)(b * 8 + zh)) * 65536;

  // Q fragments (shared by phase 0 and phase 1)
  bf16x8 af[2][2];
#pragma unroll
  for (int fm = 0; fm < 2; ++fm)
#pragma unroll
    for (int ks = 0; ks < 2; ++ks)
      af[fm][ks] = *(const bf16x8*)(Qb + (long)(fm * 16 + lrow) * 512 + ks * 32 + lq * 8);

  // ---- phase 0: T = Q_tile @ RELP^T -> LDS ----
  {
    const int u0w = w * 144;
#pragma unroll
    for (int fnT = 0; fnT < 9; ++fnT) {
      const int u0 = u0w + fnT * 16;
      floatx4 tacc[2] = {};
#pragma unroll
      for (int ks = 0; ks < 2; ++ks) {
        bf16x8 br = *(const bf16x8*)(RELP + (long)(u0 + lrow) * 64 + ks * 32 + lq * 8);
        tacc[0] = __builtin_amdgcn_mfma_f32_16x16x32_bf16(af[0][ks], br, tacc[0], 0, 0, 0);
        tacc[1] = __builtin_amdgcn_mfma_f32_16x16x32_bf16(af[1][ks], br, tacc[1], 0, 0, 0);
      }
#pragma unroll
      for (int fm = 0; fm < 2; ++fm)
#pragma unroll
        for (int r = 0; r < 4; ++r)
          Tls[(fm * 16 + lq * 4 + r) * LDT + u0 + lrow] = f2b(tacc[fm][r]);
    }
  }
  __syncthreads();

  // ---- phase 1: S = Q K^T (f32 in regs) + bias from T ----
  floatx4 sacc[2][8] = {};
#pragma unroll
  for (int fn = 0; fn < 8; ++fn) {
#pragma unroll
    for (int ks = 0; ks < 2; ++ks) {
      bf16x8 bk = *(const bf16x8*)(Kb + (long)(j0w + fn * 16 + lrow) * 1024 + ks * 32 + lq * 8);
      sacc[0][fn] = __builtin_amdgcn_mfma_f32_16x16x32_bf16(af[0][ks], bk, sacc[0][fn], 0, 0, 0);
      sacc[1][fn] = __builtin_amdgcn_mfma_f32_16x16x32_bf16(af[1][ks], bk, sacc[1][fn], 0, 0, 0);
    }
  }

  // rel-pos bias gather from LDS: bias[i][j] = T[i_local][clip(i-j,+-512)+512]
#pragma unroll
  for (int fm = 0; fm < 2; ++fm)
#pragma unroll
    for (int r = 0; r < 4; ++r) {
      const int il = fm * 16 + lq * 4 + r;
      const bf16_t* trow = Tls + il * LDT + 512;
      const int tb = i0 + il - j0w - lrow;
#pragma unroll
      for (int fn = 0; fn < 8; ++fn) {
        int t = tb - fn * 16;
        t = t < -512 ? -512 : (t > 512 ? 512 : t);
        sacc[fm][fn][r] += b2f(trow[t]);
      }
    }

  // ---- phase 2: exact softmax over full row (1024) ----
  float rmax[2][4];
#pragma unroll
  for (int fm = 0; fm < 2; ++fm)
#pragma unroll
    for (int r = 0; r < 4; ++r) {
      float m = sacc[fm][0][r];
#pragma unroll
      for (int fn = 1; fn < 8; ++fn) m = fmaxf(m, sacc[fm][fn][r]);
      rmax[fm][r] = m;
    }
#pragma unroll
  for (int off = 1; off < 16; off <<= 1)
#pragma unroll
    for (int fm = 0; fm < 2; ++fm)
#pragma unroll
      for (int r = 0; r < 4; ++r)
        rmax[fm][r] = fmaxf(rmax[fm][r], __shfl_xor(rmax[fm][r], off));
  if (lrow == 0)
#pragma unroll
    for (int fm = 0; fm < 2; ++fm)
#pragma unroll
      for (int r = 0; r < 4; ++r)
        scr[(fm * 16 + lq * 4 + r) * 9 + w] = rmax[fm][r];
  __syncthreads();
  if (tid < 32) {
    const float* rr = scr + tid * 9;
    float m = rr[0];
#pragma unroll
    for (int ww = 1; ww < 8; ++ww) m = fmaxf(m, rr[ww]);
    scr[288 + tid] = m;
  }
  __syncthreads();

  float rsum[2][4];
#pragma unroll
  for (int fm = 0; fm < 2; ++fm)
#pragma unroll
    for (int r = 0; r < 4; ++r) {
      const float m = scr[288 + fm * 16 + lq * 4 + r];
      float s = 0.f;
#pragma unroll
      for (int fn = 0; fn < 8; ++fn) {
        float e = __expf(sacc[fm][fn][r] - m);
        sacc[fm][fn][r] = e;
        s += e;
      }
      rsum[fm][r] = s;
    }
#pragma unroll
  for (int off = 1; off < 16; off <<= 1)
#pragma unroll
    for (int fm = 0; fm < 2; ++fm)
#pragma unroll
      for (int r = 0; r < 4; ++r)
        rsum[fm][r] += __shfl_xor(rsum[fm][r], off);
  if (lrow == 0)
#pragma unroll
    for (int fm = 0; fm < 2; ++fm)
#pragma unroll
      for (int r = 0; r < 4; ++r)
        scr[320 + (fm * 16 + lq * 4 + r) * 9 + w] = rsum[fm][r];
  __syncthreads();
  if (tid < 32) {
    const float* rr = scr + 320 + tid * 9;
    float s = rr[0];
#pragma unroll
    for (int ww = 1; ww < 8; ++ww) s += rr[ww];
    scr[608 + tid] = 1.f / s;
  }
  __syncthreads();
  float inv[2][4];
#pragma unroll
  for (int fm = 0; fm < 2; ++fm)
#pragma unroll
    for (int r = 0; r < 4; ++r)
      inv[fm][r] = scr[608 + fm * 16 + lq * 4 + r];
  __syncthreads();   // all T gathers + scr reads done -> safe to alias P over T

  // ---- phase 3a: P -> LDS (bf16, XOR swizzle ^((i&7)<<4); wave-local slab) ----
#pragma unroll
  for (int fm = 0; fm < 2; ++fm)
#pragma unroll
    for (int fn = 0; fn < 8; ++fn)
#pragma unroll
      for (int r = 0; r < 4; ++r) {
        const int i = fm * 16 + lq * 4 + r;
        const int j = j0w + fn * 16 + lrow;
        const unsigned boff = (unsigned)(i * 2048 + j * 2) ^ ((unsigned)(i & 7) << 4);
        *(bf16_t*)((char*)Tls + boff) = f2b(sacc[fm][fn][r] * inv[fm][r]);
      }
  // no barrier needed: each wave reads back only its own slab

  // ---- phase 3b: O partials = P_slab @ V_slab ----
  floatx4 oacc[2][4] = {};
#pragma unroll
  for (int ks = 0; ks < 4; ++ks) {
    const int j = j0w + ks * 32;
    bf16x8 ap[2];
#pragma unroll
    for (int fm = 0; fm < 2; ++fm) {
      const int i = fm * 16 + lrow;
      const unsigned boff = (unsigned)(i * 2048 + (j + lq * 8) * 2) ^ ((unsigned)(i & 7) << 4);
      ap[fm] = *(const bf16x8*)((char*)Tls + boff);
    }
#pragma unroll
    for (int fd = 0; fd < 4; ++fd) {
      bf16x8 bv = *(const bf16x8*)(VTb + (long)(fd * 16 + lrow) * 1024 + j + lq * 8);
      oacc[0][fd] = __builtin_amdgcn_mfma_f32_16x16x32_bf16(ap[0], bv, oacc[0][fd], 0, 0, 0);
      oacc[1][fd] = __builtin_amdgcn_mfma_f32_16x16x32_bf16(ap[1], bv, oacc[1][fd], 0, 0, 0);
    }
  }
  __syncthreads();   // all PV reads of P done -> safe to overwrite with partials

  // partials: per-wave f32 [i][64] at float offset w*2048 (re-aliases LDS)
  {
    float* part = (float*)Tls + w * 2048;
#pragma unroll
    for (int fm = 0; fm < 2; ++fm)
#pragma unroll
      for (int fd = 0; fd < 4; ++fd)
#pragma unroll
        for (int r = 0; r < 4; ++r)
          part[(fm * 16 + lq * 4 + r) * 64 + fd * 16 + lrow] = oacc[fm][fd][r];
  }
  __syncthreads();

  // K-reduce 8 partials, write O
  {
    const int i = tid >> 4;
    const int d0 = (tid & 15) * 4;
    floatx4 s = {};
#pragma unroll
    for (int ww = 0; ww < 8; ++ww)
      s += *(const floatx4*)((const float*)Tls + ww * 2048 + i * 64 + d0);
    hbf4 o4;
#pragma unroll
    for (int m = 0; m < 4; ++m) o4.h[m] = f2b(s[m]);
    *(hbf4*)(O + (long)(b * 1024 + i0 + i) * 512 + zh * 64 + d0) = o4;
  }
}

// ---------------------------------------------------------------- glue kernels
__global__ __launch_bounds__(256) void diag_kernel(float* __restrict__ out, long n, float v) {
  long i = (long)blockIdx.x * 256 + threadIdx.x;
  if (i < n) out[i] = v;
}

__global__ __launch_bounds__(256) void copy_kernel(const float* __restrict__ x, float* __restrict__ X) {
  long idx = ((long)blockIdx.x * 256 + threadIdx.x) * 4;
  *(float4*)(X + idx) = *(const float4*)(x + idx);
}

// pad rel [1025,64] f32 -> RELP [1152,64] bf16 (zero tail)
__global__ __launch_bounds__(256) void relpad_kernel(const float* __restrict__ rel, bf16_t* __restrict__ RELP) {
  int i = blockIdx.x * 256 + threadIdx.x;
  if (i < 73728) {
    int r = i >> 6, c = i & 63;
    RELP[i] = (r < 1025) ? f2b(rel[r * 64 + c]) : f2b(0.f);
  }
}

template <bool F32OUT>
__global__ __launch_bounds__(256) void ln_kernel(const float* __restrict__ X, const float* __restrict__ gam,
                                                 const float* __restrict__ bet, void* __restrict__ outv) {
  int row = blockIdx.x, tid = threadIdx.x;
  const float* x = X + (long)row * 512;
  float a = x[tid], b = x[tid + 256];
  float s = a + b, q = a * a + b * b;
  for (int off = 32; off; off >>= 1) { s += __shfl_down(s, off); q += __shfl_down(q, off); }
  __shared__ float red[8];
  int w = tid >> 6;
  if ((tid & 63) == 0) { red[w] = s; red[w + 4] = q; }
  __syncthreads();
  float ts = red[0] + red[1] + red[2] + red[3];
  float tq = red[4] + red[5] + red[6] + red[7];
  float mean = ts * (1.f / 512.f);
  float var = tq * (1.f / 512.f) - mean * mean;
  float rs = rsqrtf(var + 1e-5f);
  float o0 = (a - mean) * rs * gam[tid]       + bet[tid];
  float o1 = (b - mean) * rs * gam[tid + 256] + bet[tid + 256];
  if constexpr (F32OUT) {
    float* out = (float*)outv;
    out[(long)row * 512 + tid]       = o0;
    out[(long)row * 512 + tid + 256] = o1;
  } else {
    bf16_t* out = (bf16_t*)outv;
    out[(long)row * 512 + tid]       = f2b(o0);
    out[(long)row * 512 + tid + 256] = f2b(o1);
  }
}

__global__ __launch_bounds__(256) void transpose_kernel(const float* __restrict__ in, bf16_t* __restrict__ out,
                                                        int R, int C) {
  __shared__ float t[32][33];
  int c0 = blockIdx.x * 32, r0 = blockIdx.y * 32;
  int tx = threadIdx.x & 31, ty = threadIdx.x >> 5;
#pragma unroll
  for (int i = 0; i < 4; ++i)
    t[ty + i * 8][tx] = in[(long)(r0 + ty + i * 8) * C + c0 + tx];
  __syncthreads();
#pragma unroll
  for (int i = 0; i < 4; ++i)
    out[(long)(c0 + ty + i * 8) * R + r0 + tx] = f2b(t[tx][ty + i * 8]);
}

// VT[z=b*8+h][d][j] = KV[(b*1024+j)*1024 + 512 + h*64 + d]
__global__ __launch_bounds__(256) void vt_kernel(const bf16_t* __restrict__ KV, bf16_t* __restrict__ VT) {
  int jb = blockIdx.x, z = blockIdx.y;
  int b = z >> 3, h = z & 7;
  const bf16_t* src = KV + (long)b * 1024 * 1024 + 512 + h * 64;
  bf16_t* dst = VT + (long)z * 65536;
  __shared__ bf16_t t[64][65];
  int tid = threadIdx.x;
#pragma unroll
  for (int i = 0; i < 16; ++i) {
    int l = i * 256 + tid;
    int j = l >> 6, d = l & 63;
    t[d][j] = src[(long)(jb * 64 + j) * 1024 + d];
  }
  __syncthreads();
#pragma unroll
  for (int i = 0; i < 16; ++i) {
    int l = i * 256 + tid;
    int d = l >> 6, j = l & 63;
    dst[(long)d * 1024 + jb * 64 + j] = t[d][j];
  }
}

__global__ __launch_bounds__(256) void glu_kernel(const bf16_t* __restrict__ P, bf16_t* __restrict__ out) {
  long idx = ((long)blockIdx.x * 256 + threadIdx.x) * 8;
  long r = idx >> 10;
  int c = (int)(idx & 1023);
  hbf8 a = *(const hbf8*)(P + r * 2048 + c);
  hbf8 g = *(const hbf8*)(P + r * 2048 + 1024 + c);
  hbf8 o;
#pragma unroll
  for (int i = 0; i < 8; ++i) o.h[i] = f2b(b2f(a.h[i]) * sig_(b2f(g.h[i])));
  *(hbf8*)(out + idx) = o;
}

__global__ __launch_bounds__(256) void dwconv_kernel(const bf16_t* __restrict__ G, const float* __restrict__ dw,
    const float* __restrict__ db, const float* __restrict__ bng, const float* __restrict__ bnb,
    const float* __restrict__ bnm, const float* __restrict__ bnv, bf16_t* __restrict__ out) {
  int n0 = blockIdx.x * 32, c0 = blockIdx.y * 64, b = blockIdx.z;
  __shared__ bf16_t t[62][64];
  __shared__ float dws[31][64];
  int tid = threadIdx.x;
  const bf16_t* src = G + (long)b * 1024 * 1024 + c0;
#pragma unroll
  for (int i = 0; i < 16; ++i) {
    int l = i * 256 + tid;
    if (l < 3968) {
      int rr = l >> 6, c = l & 63;
      int n = n0 - 15 + rr;
      t[rr][c] = (n >= 0 && n < 1024) ? src[(long)n * 1024 + c] : f2b(0.f);
    }
  }
#pragma unroll
  for (int i = 0; i < 8; ++i) {
    int l = i * 256 + tid;
    if (l < 1984) {
      int k = l >> 6, c = l & 63;
      dws[k][c] = dw[(long)(c0 + c) * 31 + k];
    }
  }
  __syncthreads();
  int c = tid & 63, nl = tid >> 6;
  float rs = rsqrtf(bnv[c0 + c] + 1e-5f);
  float sc = rs * bng[c0 + c];
  float ab = (db[c0 + c] - bnm[c0 + c]) * sc + bnb[c0 + c];
#pragma unroll
  for (int j = 0; j < 8; ++j) {
    int rr = nl * 8 + j;
    float s = 0.f;
#pragma unroll
    for (int k = 0; k < 31; ++k) s += b2f(t[rr + k][c]) * dws[k][c];
    float y = s * sc + ab;
    out[((long)b * 1024 + n0 + rr) * 1024 + c0 + c] = f2b(y * sig_(y));
  }
}

// ---------------------------------------------------------------- launch
extern "C" void kernel_launch(void* const* d_in, const int* in_sizes, int n_in,
                              void* d_out, int out_size, void* d_ws, size_t ws_size,
                              hipStream_t stream) {
  auto fail = [&](float code) {
    diag_kernel<<<(out_size + 255) / 256, 256, 0, stream>>>((float*)d_out, out_size, code);
  };
  if (n_in != 34)             { fail(70.f);  return; }
  if (in_sizes[0] != 4194304) { fail(80.f);  return; }

  const float* x     = (const float*)d_in[0];
  const float* f1_g  = (const float*)d_in[1];
  const float* f1_b  = (const float*)d_in[2];
  const float* f1_w1 = (const float*)d_in[3];
  const float* f1_b1 = (const float*)d_in[4];
  const float* f1_w2 = (const float*)d_in[5];
  const float* f1_b2 = (const float*)d_in[6];
  const float* a_g   = (const float*)d_in[7];
  const float* a_b   = (const float*)d_in[8];
  const float* wq    = (const float*)d_in[9];
  const float* wkv   = (const float*)d_in[10];
  const float* wo    = (const float*)d_in[11];
  const float* wo_b  = (const float*)d_in[12];
  const float* rel   = (const float*)d_in[13];
  const float* c_g   = (const float*)d_in[14];
  const float* c_b   = (const float*)d_in[15];
  const float* cw1   = (const float*)d_in[16];
  const float* cb1   = (const float*)d_in[17];
  const float* dwp   = (const float*)d_in[18];
  const float* dbp   = (const float*)d_in[19];
  const float* bn_g  = (const float*)d_in[20];
  const float* bn_b  = (const float*)d_in[21];
  const float* bn_m  = (const float*)d_in[22];
  const float* bn_v  = (const float*)d_in[23];
  const float* cw2   = (const float*)d_in[24];
  const float* cb2   = (const float*)d_in[25];
  const float* f2_g  = (const float*)d_in[26];
  const float* f2_b  = (const float*)d_in[27];
  const float* f2_w1 = (const float*)d_in[28];
  const float* f2_b1 = (const float*)d_in[29];
  const float* f2_w2 = (const float*)d_in[30];
  const float* f2_b2 = (const float*)d_in[31];
  const float* p_g   = (const float*)d_in[32];
  const float* p_b   = (const float*)d_in[33];

  // ---- workspace arena ----
  // X 16.78M | WT 13.63M | D 33.55M {Q,KV,VT}/{GLU,DWO} | E: MID 33.55M | RELP 147K
  char* ws = (char*)d_ws;
  const size_t OFF_X  = 0;
  const size_t OFF_WT = 16777216;
  const size_t OFF_D  = 30408704;
  const size_t OFF_E  = 63963136;
  const size_t relp_off = OFF_E + 33554432;
  if (ws_size < relp_off + 147456ULL) { fail(200.f); return; }

  float*  X   = (float*)(ws + OFF_X);
  bf16_t* WT  = (bf16_t*)(ws + OFF_WT);
  bf16_t* Q   = (bf16_t*)(ws + OFF_D);
  bf16_t* KV  = (bf16_t*)(ws + OFF_D + 8388608);
  bf16_t* VT  = (bf16_t*)(ws + OFF_D + 25165824);
  bf16_t* GLU = (bf16_t*)(ws + OFF_D);
  bf16_t* DWO = (bf16_t*)(ws + OFF_D + 16777216);
  bf16_t* MID = (bf16_t*)(ws + OFF_E);
  bf16_t* RELP= (bf16_t*)(ws + relp_off);
  bf16_t* H   = (bf16_t*)d_out;   // bf16 scratch inside f32 out buffer
  bf16_t* O   = (bf16_t*)d_out;   // final f32 LN overwrites at the end

  bf16_t* f1_w1t = WT;            bf16_t* f1_w2t = WT + 1048576;
  bf16_t* wqt    = WT + 2097152;  bf16_t* wkvt   = WT + 2359296;
  bf16_t* wot    = WT + 2883584;  bf16_t* cw1t   = WT + 3145728;
  bf16_t* cw2t   = WT + 4194304;  bf16_t* f2_w1t = WT + 4718592;
  bf16_t* f2_w2t = WT + 5767168;

  auto GA = [](const bf16_t* A, const bf16_t* Bt, const float* bias, bf16_t* C,
               float* resid, const bf16_t* qr, int K, int lda, int ldb, int ldc,
               float alpha, float beta) {
    GemmArgs g{}; g.A = A; g.Bt = Bt; g.bias = bias; g.qr = qr; g.C = C; g.resid = resid;
    g.K = K; g.lda = lda; g.ldb = ldb; g.ldc = ldc; g.ldqr = 1152;
    g.sAb = g.sAh = g.sBb = g.sBh = g.sCb = g.sCh = 0; g.alpha = alpha; g.beta = beta;
    return g;
  };
  auto T = [&](const float* in, bf16_t* out, int R, int C) {
    transpose_kernel<<<dim3(C / 32, R / 32), 256, 0, stream>>>(in, out, R, C);
  };

  copy_kernel<<<4096, 256, 0, stream>>>(x, X);
  relpad_kernel<<<288, 256, 0, stream>>>(rel, RELP);
  T(f1_w1, f1_w1t, 512, 2048);  T(f1_w2, f1_w2t, 2048, 512);
  T(wq, wqt, 512, 512);         T(wkv, wkvt, 512, 1024);
  T(wo, wot, 512, 512);         T(cw1, cw1t, 512, 2048);
  T(cw2, cw2t, 1024, 512);      T(f2_w1, f2_w1t, 512, 2048);
  T(f2_w2, f2_w2t, 2048, 512);

  // ---- FF1 half-step ----
  ln_kernel<false><<<8192, 256, 0, stream>>>(X, f1_g, f1_b, H);
  { GemmArgs g = GA(H, f1_w1t, f1_b1, MID, nullptr, nullptr, 512, 512, 512, 2048, 1.f, 0.f);
    gemm_bt<128, 128, 2, 2, 1><<<dim3(16, 64, 1), 256, 0, stream>>>(g); }
  { GemmArgs g = GA(MID, f1_w2t, f1_b2, nullptr, X, nullptr, 2048, 2048, 2048, 512, 1.f, 0.5f);
    gemm_bt<64, 128, 1, 4, 2><<<dim3(4, 128, 1), 256, 0, stream>>>(g); }

  // ---- attention ----
  ln_kernel<false><<<8192, 256, 0, stream>>>(X, a_g, a_b, H);
  { GemmArgs g = GA(H, wqt, nullptr, Q, nullptr, nullptr, 512, 512, 512, 512, 0.125f, 0.f);
    gemm_bt<128, 128, 2, 2, 0><<<dim3(4, 64, 1), 256, 0, stream>>>(g); }   // q (scale folded)
  { GemmArgs g = GA(H, wkvt, nullptr, KV, nullptr, nullptr, 512, 512, 512, 1024, 1.f, 0.f);
    gemm_bt<128, 128, 2, 2, 0><<<dim3(8, 64, 1), 256, 0, stream>>>(g); }   // k|v
  vt_kernel<<<dim3(16, 64), 256, 0, stream>>>(KV, VT);

  // fused: T=q@rel^T (in-LDS), S = qk^T + bias, softmax, O = P @ V
  attn_kernel<<<dim3(32, 64), 512, 0, stream>>>(Q, KV, VT, RELP, O);

  { GemmArgs g = GA(O, wot, wo_b, nullptr, X, nullptr, 512, 512, 512, 512, 1.f, 1.f);
    gemm_bt<64, 128, 1, 4, 2><<<dim3(4, 128, 1), 256, 0, stream>>>(g); }   // x += o@wo + b

  // ---- conv module ----
  ln_kernel<false><<<8192, 256, 0, stream>>>(X, c_g, c_b, H);
  { GemmArgs g = GA(H, cw1t, cb1, MID, nullptr, nullptr, 512, 512, 512, 2048, 1.f, 0.f);
    gemm_bt<128, 128, 2, 2, 0><<<dim3(16, 64, 1), 256, 0, stream>>>(g); }  // pw1 + bias
  glu_kernel<<<4096, 256, 0, stream>>>(MID, GLU);
  dwconv_kernel<<<dim3(32, 16, 8), 256, 0, stream>>>(GLU, dwp, dbp, bn_g, bn_b, bn_m, bn_v, DWO);
  { GemmArgs g = GA(DWO, cw2t, cb2, nullptr, X, nullptr, 1024, 1024, 1024, 512, 1.f, 1.f);
    gemm_bt<64, 128, 1, 4, 2><<<dim3(4, 128, 1), 256, 0, stream>>>(g); }   // x += h@cw2 + b

  // ---- FF2 half-step + post-LN (f32 out) ----
  ln_kernel<false><<<8192, 256, 0, stream>>>(X, f2_g, f2_b, H);
  { GemmArgs g = GA(H, f2_w1t, f2_b1, MID, nullptr, nullptr, 512, 512, 512, 2048, 1.f, 0.f);
    gemm_bt<128, 128, 2, 2, 1><<<dim3(16, 64, 1), 256, 0, stream>>>(g); }
  { GemmArgs g = GA(MID, f2_w2t, f2_b2, nullptr, X, nullptr, 2048, 2048, 2048, 512, 1.f, 0.5f);
    gemm_bt<64, 128, 1, 4, 2><<<dim3(4, 128, 1), 256, 0, stream>>>(g); }
  ln_kernel<true><<<8192, 256, 0, stream>>>(X, p_g, p_b, (float*)d_out);
}

// Round 3
// 665.911 us; speedup vs baseline: 1.2885x; 1.0376x over previous
//
#include <hip/hip_runtime.h>
#include <hip/hip_bf16.h>
#include <cstdint>

// Conformer block, MI355X gfx950. f32 inputs, f32 output, bf16 MFMA internals.
// B=8 N=1024 D=512 H=8 DH=64 FF=2048 CI=1024 K=31 MPE=512.
// Round 12: attn latency attack — register-prefetch batches (VGPR 52->~120),
// XCD-chunked block swizzle (attn + gemm), LDT 1028, 5 barriers (was 9).

using bf16_t = __hip_bfloat16;
typedef __bf16 bf16x8 __attribute__((ext_vector_type(8)));
typedef float floatx4 __attribute__((ext_vector_type(4)));

struct alignas(16) hbf8 { bf16_t h[8]; };
struct alignas(8)  hbf4 { bf16_t h[4]; };

__device__ __forceinline__ float  b2f(bf16_t h) { return __bfloat162float(h); }
__device__ __forceinline__ bf16_t f2b(float f)  { return __float2bfloat16(f); }
__device__ __forceinline__ float  sig_(float x) { return 1.f / (1.f + __expf(-x)); }

// async global->LDS, 16B/lane; LDS dest must be wave-uniform base + lane*16 (m97 pattern)
__device__ __forceinline__ void async16(const void* g, void* l) {
  __builtin_amdgcn_global_load_lds(
      (const __attribute__((address_space(1))) unsigned int*)(uintptr_t)g,
      (__attribute__((address_space(3))) unsigned int*)(uintptr_t)l, 16, 0, 0);
}

// ---------------------------------------------------------------- GEMM (MFMA)
// C[M,N] = A[M,K] @ Bt[N,K]^T   (bf16 operands, k-contiguous, f32 accum)
// EPI 0: C_bf16 = alpha*acc + bias     EPI 1: C_bf16 = swish(acc + bias)
// EPI 2: resid_f32 += beta*(acc+bias)
struct GemmArgs {
  const bf16_t* A; const bf16_t* Bt; const float* bias; const bf16_t* qr;
  bf16_t* C; float* resid;
  int K, lda, ldb, ldc, ldqr;
  long sAb, sAh, sBb, sBh, sCb, sCh;
  float alpha, beta;
};

template <int BM, int BN, int WR, int WC, int EPI>
__global__ __launch_bounds__(256) void gemm_bt(GemmArgs g) {
  constexpr int FM = BM / (WR * 16);
  constexpr int FN = BN / (WC * 16);
  constexpr int IA = (BM * 4) / 256;
  constexpr int IB = (BN * 4) / 256;
  __shared__ __align__(16) bf16_t As[BM * 32];
  __shared__ __align__(16) bf16_t Bs[BN * 32];
  const int tid = threadIdx.x;
  const int lane = tid & 63, w = tid >> 6;
  // XCD-chunked bijective remap (nwg % 8 == 0 for all our launches):
  // consecutive dispatch ids round-robin XCDs; give each XCD a contiguous
  // run of logical tiles so the A-panel + B working set stays in its L2.
  int bx = blockIdx.x, by = blockIdx.y;
  {
    const int gx = gridDim.x;
    const int nwg = gx * gridDim.y;
    if ((nwg & 7) == 0 && gridDim.z == 1) {
      int lin = by * gx + bx;
      int lid = (lin & 7) * (nwg >> 3) + (lin >> 3);
      bx = lid % gx; by = lid / gx;
    }
  }
  const int bm0 = by * BM, bn0 = bx * BN;
  const int zb = blockIdx.z >> 3, zh = blockIdx.z & 7;
  const bf16_t* Ab = g.A + (long)zb * g.sAb + (long)zh * g.sAh;
  const bf16_t* Bb = g.Bt + (long)zb * g.sBb + (long)zh * g.sBh;
  const int wm0 = (w / WC) * (FM * 16);
  const int wn0 = (w % WC) * (FN * 16);
  const int lrow = lane & 15, lq = lane >> 4;

  floatx4 acc[FM][FN] = {};

  for (int k0 = 0; k0 < g.K; k0 += 32) {
#pragma unroll
    for (int i = 0; i < IA; ++i) {
      int c = i * 256 + tid;
      int m = c >> 2, kk = (c & 3) * 8;
      async16(Ab + (long)(bm0 + m) * g.lda + (k0 + kk), (char*)As + c * 16);
    }
#pragma unroll
    for (int i = 0; i < IB; ++i) {
      int c = i * 256 + tid;
      int n = bn0 + (c >> 2), kk = (c & 3) * 8;
      async16(Bb + (long)n * g.ldb + (k0 + kk), (char*)Bs + c * 16);
    }
    __syncthreads();   // drains vmcnt before s_barrier (compiler-inserted)
    bf16x8 af[FM], bfr[FN];
#pragma unroll
    for (int fm = 0; fm < FM; ++fm)
      af[fm] = *(const bf16x8*)(As + (wm0 + fm * 16 + lrow) * 32 + lq * 8);
#pragma unroll
    for (int fn = 0; fn < FN; ++fn)
      bfr[fn] = *(const bf16x8*)(Bs + (wn0 + fn * 16 + lrow) * 32 + lq * 8);
#pragma unroll
    for (int fm = 0; fm < FM; ++fm)
#pragma unroll
      for (int fn = 0; fn < FN; ++fn)
        acc[fm][fn] = __builtin_amdgcn_mfma_f32_16x16x32_bf16(af[fm], bfr[fn], acc[fm][fn], 0, 0, 0);
    __syncthreads();
  }

  const int bi = bm0 + wm0 + lq * 4;    // + fm*16 + r
  const int bj = bn0 + wn0 + lrow;      // + fn*16
  if constexpr (EPI == 2) {
    float* R = g.resid;
#pragma unroll
    for (int fm = 0; fm < FM; ++fm)
#pragma unroll
      for (int fn = 0; fn < FN; ++fn) {
        int j = bj + fn * 16;
        float bv = g.bias ? g.bias[j] : 0.f;
#pragma unroll
        for (int r = 0; r < 4; ++r) {
          long i = bi + fm * 16 + r;
          R[i * g.ldc + j] += g.beta * (acc[fm][fn][r] + bv);
        }
      }
  } else {
    bf16_t* C = g.C + (long)zb * g.sCb + (long)zh * g.sCh;
#pragma unroll
    for (int fm = 0; fm < FM; ++fm)
#pragma unroll
      for (int fn = 0; fn < FN; ++fn) {
        int j = bj + fn * 16;
        float bv = g.bias ? g.bias[j] : 0.f;
#pragma unroll
        for (int r = 0; r < 4; ++r) {
          int i = bi + fm * 16 + r;
          float v = acc[fm][fn][r];
          if constexpr (EPI == 0) v = g.alpha * v + bv;
          if constexpr (EPI == 1) { v += bv; v = v * sig_(v); }
          C[(long)i * g.ldc + j] = f2b(v);
        }
      }
  }
}

// ---------------------------------------------------------------- fused attention
// One block = one (z = b*8+h, 32-row i-tile). 512 threads = 8 waves.
// Wave w owns j-slab [w*128, w*128+128).
// Phase 0: T[i][u] = q_i . rel_u via MFMA into LDS (u-slab w*144..; only
//          u < 1028 kept — gather reads only u in [0,1024]).
// Phase 1: S = Q K^T (regs, K prefetched in 2x8-fragment batches) + bias from T.
// Phase 2: exact softmax; cross-wave reduce via per-thread 8-way LDS broadcast.
// Phase 3: P -> LDS bf16 (XOR-swizzled, aliases T), PV with VT prefetched in
//          2x8-fragment batches, K-split partials reduced through LDS.
// Q: bf16 [(b*1024+i)*512 + h*64 + d] (pre-scaled by 1/8)
// KV: bf16 [(b*1024+j)*1024 + h*64 + d] (K half)
// VT: bf16 [(b*8+h)*65536 + d*1024 + j]
// RELP: bf16 [1152][64] (rows >=1025 zero)
// O: bf16 [(b*1024+i)*512 + h*64 + d]
__global__ __launch_bounds__(512, 4) void attn_kernel(
    const bf16_t* __restrict__ Q, const bf16_t* __restrict__ KV,
    const bf16_t* __restrict__ VT, const bf16_t* __restrict__ RELP,
    bf16_t* __restrict__ O) {
  constexpr int LDT = 1028;                         // 2056 B row -> 2-bank rotate
  __shared__ __align__(16) bf16_t Tls[32 * LDT];    // 65792 B; aliased: T -> P -> partials
  __shared__ float scr[576];  // [0,288) rmax red (stride 9), [288,576) sum red

  const int tid = threadIdx.x;
  const int w = tid >> 6, lane = tid & 63;
  const int lrow = lane & 15, lq = lane >> 4;
  // XCD-chunked remap: 2048 blocks; each XCD gets all 32 i-tiles of 8 z's
  // so K/VT/RELP panels stay resident in that XCD's L2.
  const int lin = blockIdx.y * gridDim.x + blockIdx.x;   // gridDim.x = 32
  const int lid = (lin & 7) * 256 + (lin >> 3);
  const int z = lid >> 5;
  const int i0 = (lid & 31) * 32;
  const int b = z >> 3, zh = z & 7;
  const int j0w = w * 128;

  const bf16_t* Qb  = Q  + ((long)(b * 1024 + i0)) * 512 + zh * 64;
  const bf16_t* Kb  = KV + ((long)b * 1024) * 1024 + zh * 64;
  const bf16_t* VTb = VT + ((long)(b * 8 + zh)) * 65536;

  // Q fragments (shared by phase 0 and phase 1)
  bf16x8 af[2][2];
#pragma unroll
  for (int fm = 0; fm < 2; ++fm)
#pragma unroll
    for (int ks = 0; ks < 2; ++ks)
      af[fm][ks] = *(const bf16x8*)(Qb + (long)(fm * 16 + lrow) * 512 + ks * 32 + lq * 8);

  // ---- phase 0: T = Q_tile @ RELP^T -> LDS (all 18 RELP frags prefetched) ----
  {
    const int u0w = w * 144;
    bf16x8 rf[18];
#pragma unroll
    for (int fnT = 0; fnT < 9; ++fnT) {
      const int u0 = u0w + fnT * 16;
      if (u0 < LDT) {
        rf[2 * fnT]     = *(const bf16x8*)(RELP + (long)(u0 + lrow) * 64 + lq * 8);
        rf[2 * fnT + 1] = *(const bf16x8*)(RELP + (long)(u0 + lrow) * 64 + 32 + lq * 8);
      }
    }
#pragma unroll
    for (int fnT = 0; fnT < 9; ++fnT) {
      const int u0 = u0w + fnT * 16;
      if (u0 < LDT) {
        floatx4 tacc[2] = {};
        tacc[0] = __builtin_amdgcn_mfma_f32_16x16x32_bf16(af[0][0], rf[2 * fnT],     tacc[0], 0, 0, 0);
        tacc[0] = __builtin_amdgcn_mfma_f32_16x16x32_bf16(af[0][1], rf[2 * fnT + 1], tacc[0], 0, 0, 0);
        tacc[1] = __builtin_amdgcn_mfma_f32_16x16x32_bf16(af[1][0], rf[2 * fnT],     tacc[1], 0, 0, 0);
        tacc[1] = __builtin_amdgcn_mfma_f32_16x16x32_bf16(af[1][1], rf[2 * fnT + 1], tacc[1], 0, 0, 0);
        const int uu = u0 + lrow;
#pragma unroll
        for (int fm = 0; fm < 2; ++fm)
#pragma unroll
          for (int r = 0; r < 4; ++r)
            if (uu < LDT)
              Tls[(fm * 16 + lq * 4 + r) * LDT + uu] = f2b(tacc[fm][r]);
      }
    }
  }

  // K fragment prefetch (issued before the barrier; consumed after)
  bf16x8 kfA[8], kfB[8];
#pragma unroll
  for (int x = 0; x < 8; ++x)
    kfA[x] = *(const bf16x8*)(Kb + (long)(j0w + (x >> 1) * 16 + lrow) * 1024 + (x & 1) * 32 + lq * 8);
#pragma unroll
  for (int x = 0; x < 8; ++x)
    kfB[x] = *(const bf16x8*)(Kb + (long)(j0w + (4 + (x >> 1)) * 16 + lrow) * 1024 + (x & 1) * 32 + lq * 8);
  __syncthreads();   // T visible to all waves

  // ---- phase 1: S = Q K^T (f32 in regs) + bias from T ----
  floatx4 sacc[2][8] = {};
#pragma unroll
  for (int fn = 0; fn < 4; ++fn) {
    sacc[0][fn] = __builtin_amdgcn_mfma_f32_16x16x32_bf16(af[0][0], kfA[2 * fn],     sacc[0][fn], 0, 0, 0);
    sacc[0][fn] = __builtin_amdgcn_mfma_f32_16x16x32_bf16(af[0][1], kfA[2 * fn + 1], sacc[0][fn], 0, 0, 0);
    sacc[1][fn] = __builtin_amdgcn_mfma_f32_16x16x32_bf16(af[1][0], kfA[2 * fn],     sacc[1][fn], 0, 0, 0);
    sacc[1][fn] = __builtin_amdgcn_mfma_f32_16x16x32_bf16(af[1][1], kfA[2 * fn + 1], sacc[1][fn], 0, 0, 0);
  }
#pragma unroll
  for (int fn = 4; fn < 8; ++fn) {
    sacc[0][fn] = __builtin_amdgcn_mfma_f32_16x16x32_bf16(af[0][0], kfB[2 * (fn - 4)],     sacc[0][fn], 0, 0, 0);
    sacc[0][fn] = __builtin_amdgcn_mfma_f32_16x16x32_bf16(af[0][1], kfB[2 * (fn - 4) + 1], sacc[0][fn], 0, 0, 0);
    sacc[1][fn] = __builtin_amdgcn_mfma_f32_16x16x32_bf16(af[1][0], kfB[2 * (fn - 4)],     sacc[1][fn], 0, 0, 0);
    sacc[1][fn] = __builtin_amdgcn_mfma_f32_16x16x32_bf16(af[1][1], kfB[2 * (fn - 4) + 1], sacc[1][fn], 0, 0, 0);
  }

  // rel-pos bias gather from LDS: bias[i][j] = T[i_local][clip(i-j,+-512)+512]
#pragma unroll
  for (int fm = 0; fm < 2; ++fm)
#pragma unroll
    for (int r = 0; r < 4; ++r) {
      const int il = fm * 16 + lq * 4 + r;
      const bf16_t* trow = Tls + il * LDT + 512;
      const int tb = i0 + il - j0w - lrow;
#pragma unroll
      for (int fn = 0; fn < 8; ++fn) {
        int t = tb - fn * 16;
        t = t < -512 ? -512 : (t > 512 ? 512 : t);
        sacc[fm][fn][r] += b2f(trow[t]);
      }
    }

  // ---- phase 2: exact softmax over full row (1024) ----
  float rmax[2][4];
#pragma unroll
  for (int fm = 0; fm < 2; ++fm)
#pragma unroll
    for (int r = 0; r < 4; ++r) {
      float m = sacc[fm][0][r];
#pragma unroll
      for (int fn = 1; fn < 8; ++fn) m = fmaxf(m, sacc[fm][fn][r]);
      rmax[fm][r] = m;
    }
#pragma unroll
  for (int off = 1; off < 16; off <<= 1)
#pragma unroll
    for (int fm = 0; fm < 2; ++fm)
#pragma unroll
      for (int r = 0; r < 4; ++r)
        rmax[fm][r] = fmaxf(rmax[fm][r], __shfl_xor(rmax[fm][r], off));
  if (lrow == 0)
#pragma unroll
    for (int fm = 0; fm < 2; ++fm)
#pragma unroll
      for (int r = 0; r < 4; ++r)
        scr[(fm * 16 + lq * 4 + r) * 9 + w] = rmax[fm][r];
  __syncthreads();

  float rsum[2][4];
#pragma unroll
  for (int fm = 0; fm < 2; ++fm)
#pragma unroll
    for (int r = 0; r < 4; ++r) {
      const float* rr = scr + (fm * 16 + lq * 4 + r) * 9;
      float m = rr[0];
#pragma unroll
      for (int ww = 1; ww < 8; ++ww) m = fmaxf(m, rr[ww]);
      float s = 0.f;
#pragma unroll
      for (int fn = 0; fn < 8; ++fn) {
        float e = __expf(sacc[fm][fn][r] - m);
        sacc[fm][fn][r] = e;
        s += e;
      }
      rsum[fm][r] = s;
    }
#pragma unroll
  for (int off = 1; off < 16; off <<= 1)
#pragma unroll
    for (int fm = 0; fm < 2; ++fm)
#pragma unroll
      for (int r = 0; r < 4; ++r)
        rsum[fm][r] += __shfl_xor(rsum[fm][r], off);
  if (lrow == 0)
#pragma unroll
    for (int fm = 0; fm < 2; ++fm)
#pragma unroll
      for (int r = 0; r < 4; ++r)
        scr[288 + (fm * 16 + lq * 4 + r) * 9 + w] = rsum[fm][r];
  __syncthreads();   // also orders: all T gathers done -> safe to alias P over T

  float inv[2][4];
#pragma unroll
  for (int fm = 0; fm < 2; ++fm)
#pragma unroll
    for (int r = 0; r < 4; ++r) {
      const float* rr = scr + 288 + (fm * 16 + lq * 4 + r) * 9;
      float s = rr[0];
#pragma unroll
      for (int ww = 1; ww < 8; ++ww) s += rr[ww];
      inv[fm][r] = 1.f / s;
    }

  // VT prefetch, first half (ks 0,1) — overlaps with the P conversion below
  bf16x8 vfA[8];
#pragma unroll
  for (int x = 0; x < 8; ++x)   // x = ks*4 + fd, ks in {0,1}
    vfA[x] = *(const bf16x8*)(VTb + (long)((x & 3) * 16 + lrow) * 1024 + j0w + (x >> 2) * 32 + lq * 8);

  // ---- phase 3a: P -> LDS (bf16, XOR swizzle ^((i&7)<<4); wave-local slab) ----
#pragma unroll
  for (int fm = 0; fm < 2; ++fm)
#pragma unroll
    for (int fn = 0; fn < 8; ++fn)
#pragma unroll
      for (int r = 0; r < 4; ++r) {
        const int i = fm * 16 + lq * 4 + r;
        const int j = j0w + fn * 16 + lrow;
        const unsigned boff = (unsigned)(i * 2048 + j * 2) ^ ((unsigned)(i & 7) << 4);
        *(bf16_t*)((char*)Tls + boff) = f2b(sacc[fm][fn][r] * inv[fm][r]);
      }
  // no barrier needed: each wave reads back only its own slab

  // VT prefetch, second half (ks 2,3)
  bf16x8 vfB[8];
#pragma unroll
  for (int x = 0; x < 8; ++x)   // x = ks*4 + fd, ks in {2,3}
    vfB[x] = *(const bf16x8*)(VTb + (long)((x & 3) * 16 + lrow) * 1024 + j0w + 64 + (x >> 2) * 32 + lq * 8);

  // ---- phase 3b: O partials = P_slab @ V_slab ----
  floatx4 oacc[2][4] = {};
#pragma unroll
  for (int ks = 0; ks < 4; ++ks) {
    const int j = j0w + ks * 32;
    bf16x8 ap[2];
#pragma unroll
    for (int fm = 0; fm < 2; ++fm) {
      const int i = fm * 16 + lrow;
      const unsigned boff = (unsigned)(i * 2048 + (j + lq * 8) * 2) ^ ((unsigned)(i & 7) << 4);
      ap[fm] = *(const bf16x8*)((char*)Tls + boff);
    }
#pragma unroll
    for (int fd = 0; fd < 4; ++fd) {
      bf16x8 bv = (ks < 2) ? vfA[(ks << 2) | fd] : vfB[((ks - 2) << 2) | fd];
      oacc[0][fd] = __builtin_amdgcn_mfma_f32_16x16x32_bf16(ap[0], bv, oacc[0][fd], 0, 0, 0);
      oacc[1][fd] = __builtin_amdgcn_mfma_f32_16x16x32_bf16(ap[1], bv, oacc[1][fd], 0, 0, 0);
    }
  }
  __syncthreads();   // all PV reads of P done -> safe to overwrite with partials

  // partials: per-wave f32 [i][64] at float offset w*2048 (re-aliases LDS)
  {
    float* part = (float*)Tls + w * 2048;
#pragma unroll
    for (int fm = 0; fm < 2; ++fm)
#pragma unroll
      for (int fd = 0; fd < 4; ++fd)
#pragma unroll
        for (int r = 0; r < 4; ++r)
          part[(fm * 16 + lq * 4 + r) * 64 + fd * 16 + lrow] = oacc[fm][fd][r];
  }
  __syncthreads();

  // K-reduce 8 partials, write O
  {
    const int i = tid >> 4;
    const int d0 = (tid & 15) * 4;
    floatx4 s = {};
#pragma unroll
    for (int ww = 0; ww < 8; ++ww)
      s += *(const floatx4*)((const float*)Tls + ww * 2048 + i * 64 + d0);
    hbf4 o4;
#pragma unroll
    for (int m = 0; m < 4; ++m) o4.h[m] = f2b(s[m]);
    *(hbf4*)(O + (long)(b * 1024 + i0 + i) * 512 + zh * 64 + d0) = o4;
  }
}

// ---------------------------------------------------------------- glue kernels
__global__ __launch_bounds__(256) void diag_kernel(float* __restrict__ out, long n, float v) {
  long i = (long)blockIdx.x * 256 + threadIdx.x;
  if (i < n) out[i] = v;
}

__global__ __launch_bounds__(256) void copy_kernel(const float* __restrict__ x, float* __restrict__ X) {
  long idx = ((long)blockIdx.x * 256 + threadIdx.x) * 4;
  *(float4*)(X + idx) = *(const float4*)(x + idx);
}

// pad rel [1025,64] f32 -> RELP [1152,64] bf16 (zero tail)
__global__ __launch_bounds__(256) void relpad_kernel(const float* __restrict__ rel, bf16_t* __restrict__ RELP) {
  int i = blockIdx.x * 256 + threadIdx.x;
  if (i < 73728) {
    int r = i >> 6, c = i & 63;
    RELP[i] = (r < 1025) ? f2b(rel[r * 64 + c]) : f2b(0.f);
  }
}

template <bool F32OUT>
__global__ __launch_bounds__(256) void ln_kernel(const float* __restrict__ X, const float* __restrict__ gam,
                                                 const float* __restrict__ bet, void* __restrict__ outv) {
  int row = blockIdx.x, tid = threadIdx.x;
  const float* x = X + (long)row * 512;
  float a = x[tid], b = x[tid + 256];
  float s = a + b, q = a * a + b * b;
  for (int off = 32; off; off >>= 1) { s += __shfl_down(s, off); q += __shfl_down(q, off); }
  __shared__ float red[8];
  int w = tid >> 6;
  if ((tid & 63) == 0) { red[w] = s; red[w + 4] = q; }
  __syncthreads();
  float ts = red[0] + red[1] + red[2] + red[3];
  float tq = red[4] + red[5] + red[6] + red[7];
  float mean = ts * (1.f / 512.f);
  float var = tq * (1.f / 512.f) - mean * mean;
  float rs = rsqrtf(var + 1e-5f);
  float o0 = (a - mean) * rs * gam[tid]       + bet[tid];
  float o1 = (b - mean) * rs * gam[tid + 256] + bet[tid + 256];
  if constexpr (F32OUT) {
    float* out = (float*)outv;
    out[(long)row * 512 + tid]       = o0;
    out[(long)row * 512 + tid + 256] = o1;
  } else {
    bf16_t* out = (bf16_t*)outv;
    out[(long)row * 512 + tid]       = f2b(o0);
    out[(long)row * 512 + tid + 256] = f2b(o1);
  }
}

__global__ __launch_bounds__(256) void transpose_kernel(const float* __restrict__ in, bf16_t* __restrict__ out,
                                                        int R, int C) {
  __shared__ float t[32][33];
  int c0 = blockIdx.x * 32, r0 = blockIdx.y * 32;
  int tx = threadIdx.x & 31, ty = threadIdx.x >> 5;
#pragma unroll
  for (int i = 0; i < 4; ++i)
    t[ty + i * 8][tx] = in[(long)(r0 + ty + i * 8) * C + c0 + tx];
  __syncthreads();
#pragma unroll
  for (int i = 0; i < 4; ++i)
    out[(long)(c0 + ty + i * 8) * R + r0 + tx] = f2b(t[tx][ty + i * 8]);
}

// VT[z=b*8+h][d][j] = KV[(b*1024+j)*1024 + 512 + h*64 + d]
__global__ __launch_bounds__(256) void vt_kernel(const bf16_t* __restrict__ KV, bf16_t* __restrict__ VT) {
  int jb = blockIdx.x, z = blockIdx.y;
  int b = z >> 3, h = z & 7;
  const bf16_t* src = KV + (long)b * 1024 * 1024 + 512 + h * 64;
  bf16_t* dst = VT + (long)z * 65536;
  __shared__ bf16_t t[64][65];
  int tid = threadIdx.x;
#pragma unroll
  for (int i = 0; i < 16; ++i) {
    int l = i * 256 + tid;
    int j = l >> 6, d = l & 63;
    t[d][j] = src[(long)(jb * 64 + j) * 1024 + d];
  }
  __syncthreads();
#pragma unroll
  for (int i = 0; i < 16; ++i) {
    int l = i * 256 + tid;
    int d = l >> 6, j = l & 63;
    dst[(long)d * 1024 + jb * 64 + j] = t[d][j];
  }
}

__global__ __launch_bounds__(256) void glu_kernel(const bf16_t* __restrict__ P, bf16_t* __restrict__ out) {
  long idx = ((long)blockIdx.x * 256 + threadIdx.x) * 8;
  long r = idx >> 10;
  int c = (int)(idx & 1023);
  hbf8 a = *(const hbf8*)(P + r * 2048 + c);
  hbf8 g = *(const hbf8*)(P + r * 2048 + 1024 + c);
  hbf8 o;
#pragma unroll
  for (int i = 0; i < 8; ++i) o.h[i] = f2b(b2f(a.h[i]) * sig_(b2f(g.h[i])));
  *(hbf8*)(out + idx) = o;
}

__global__ __launch_bounds__(256) void dwconv_kernel(const bf16_t* __restrict__ G, const float* __restrict__ dw,
    const float* __restrict__ db, const float* __restrict__ bng, const float* __restrict__ bnb,
    const float* __restrict__ bnm, const float* __restrict__ bnv, bf16_t* __restrict__ out) {
  int n0 = blockIdx.x * 32, c0 = blockIdx.y * 64, b = blockIdx.z;
  __shared__ bf16_t t[62][64];
  __shared__ float dws[31][64];
  int tid = threadIdx.x;
  const bf16_t* src = G + (long)b * 1024 * 1024 + c0;
#pragma unroll
  for (int i = 0; i < 16; ++i) {
    int l = i * 256 + tid;
    if (l < 3968) {
      int rr = l >> 6, c = l & 63;
      int n = n0 - 15 + rr;
      t[rr][c] = (n >= 0 && n < 1024) ? src[(long)n * 1024 + c] : f2b(0.f);
    }
  }
#pragma unroll
  for (int i = 0; i < 8; ++i) {
    int l = i * 256 + tid;
    if (l < 1984) {
      int k = l >> 6, c = l & 63;
      dws[k][c] = dw[(long)(c0 + c) * 31 + k];
    }
  }
  __syncthreads();
  int c = tid & 63, nl = tid >> 6;
  float rs = rsqrtf(bnv[c0 + c] + 1e-5f);
  float sc = rs * bng[c0 + c];
  float ab = (db[c0 + c] - bnm[c0 + c]) * sc + bnb[c0 + c];
#pragma unroll
  for (int j = 0; j < 8; ++j) {
    int rr = nl * 8 + j;
    float s = 0.f;
#pragma unroll
    for (int k = 0; k < 31; ++k) s += b2f(t[rr + k][c]) * dws[k][c];
    float y = s * sc + ab;
    out[((long)b * 1024 + n0 + rr) * 1024 + c0 + c] = f2b(y * sig_(y));
  }
}

// ---------------------------------------------------------------- launch
extern "C" void kernel_launch(void* const* d_in, const int* in_sizes, int n_in,
                              void* d_out, int out_size, void* d_ws, size_t ws_size,
                              hipStream_t stream) {
  auto fail = [&](float code) {
    diag_kernel<<<(out_size + 255) / 256, 256, 0, stream>>>((float*)d_out, out_size, code);
  };
  if (n_in != 34)             { fail(70.f);  return; }
  if (in_sizes[0] != 4194304) { fail(80.f);  return; }

  const float* x     = (const float*)d_in[0];
  const float* f1_g  = (const float*)d_in[1];
  const float* f1_b  = (const float*)d_in[2];
  const float* f1_w1 = (const float*)d_in[3];
  const float* f1_b1 = (const float*)d_in[4];
  const float* f1_w2 = (const float*)d_in[5];
  const float* f1_b2 = (const float*)d_in[6];
  const float* a_g   = (const float*)d_in[7];
  const float* a_b   = (const float*)d_in[8];
  const float* wq    = (const float*)d_in[9];
  const float* wkv   = (const float*)d_in[10];
  const float* wo    = (const float*)d_in[11];
  const float* wo_b  = (const float*)d_in[12];
  const float* rel   = (const float*)d_in[13];
  const float* c_g   = (const float*)d_in[14];
  const float* c_b   = (const float*)d_in[15];
  const float* cw1   = (const float*)d_in[16];
  const float* cb1   = (const float*)d_in[17];
  const float* dwp   = (const float*)d_in[18];
  const float* dbp   = (const float*)d_in[19];
  const float* bn_g  = (const float*)d_in[20];
  const float* bn_b  = (const float*)d_in[21];
  const float* bn_m  = (const float*)d_in[22];
  const float* bn_v  = (const float*)d_in[23];
  const float* cw2   = (const float*)d_in[24];
  const float* cb2   = (const float*)d_in[25];
  const float* f2_g  = (const float*)d_in[26];
  const float* f2_b  = (const float*)d_in[27];
  const float* f2_w1 = (const float*)d_in[28];
  const float* f2_b1 = (const float*)d_in[29];
  const float* f2_w2 = (const float*)d_in[30];
  const float* f2_b2 = (const float*)d_in[31];
  const float* p_g   = (const float*)d_in[32];
  const float* p_b   = (const float*)d_in[33];

  // ---- workspace arena ----
  // X 16.78M | WT 13.63M | D 33.55M {Q,KV,VT}/{GLU,DWO} | E: MID 33.55M | RELP 147K
  char* ws = (char*)d_ws;
  const size_t OFF_X  = 0;
  const size_t OFF_WT = 16777216;
  const size_t OFF_D  = 30408704;
  const size_t OFF_E  = 63963136;
  const size_t relp_off = OFF_E + 33554432;
  if (ws_size < relp_off + 147456ULL) { fail(200.f); return; }

  float*  X   = (float*)(ws + OFF_X);
  bf16_t* WT  = (bf16_t*)(ws + OFF_WT);
  bf16_t* Q   = (bf16_t*)(ws + OFF_D);
  bf16_t* KV  = (bf16_t*)(ws + OFF_D + 8388608);
  bf16_t* VT  = (bf16_t*)(ws + OFF_D + 25165824);
  bf16_t* GLU = (bf16_t*)(ws + OFF_D);
  bf16_t* DWO = (bf16_t*)(ws + OFF_D + 16777216);
  bf16_t* MID = (bf16_t*)(ws + OFF_E);
  bf16_t* RELP= (bf16_t*)(ws + relp_off);
  bf16_t* H   = (bf16_t*)d_out;   // bf16 scratch inside f32 out buffer
  bf16_t* O   = (bf16_t*)d_out;   // final f32 LN overwrites at the end

  bf16_t* f1_w1t = WT;            bf16_t* f1_w2t = WT + 1048576;
  bf16_t* wqt    = WT + 2097152;  bf16_t* wkvt   = WT + 2359296;
  bf16_t* wot    = WT + 2883584;  bf16_t* cw1t   = WT + 3145728;
  bf16_t* cw2t   = WT + 4194304;  bf16_t* f2_w1t = WT + 4718592;
  bf16_t* f2_w2t = WT + 5767168;

  auto GA = [](const bf16_t* A, const bf16_t* Bt, const float* bias, bf16_t* C,
               float* resid, const bf16_t* qr, int K, int lda, int ldb, int ldc,
               float alpha, float beta) {
    GemmArgs g{}; g.A = A; g.Bt = Bt; g.bias = bias; g.qr = qr; g.C = C; g.resid = resid;
    g.K = K; g.lda = lda; g.ldb = ldb; g.ldc = ldc; g.ldqr = 1152;
    g.sAb = g.sAh = g.sBb = g.sBh = g.sCb = g.sCh = 0; g.alpha = alpha; g.beta = beta;
    return g;
  };
  auto T = [&](const float* in, bf16_t* out, int R, int C) {
    transpose_kernel<<<dim3(C / 32, R / 32), 256, 0, stream>>>(in, out, R, C);
  };

  copy_kernel<<<4096, 256, 0, stream>>>(x, X);
  relpad_kernel<<<288, 256, 0, stream>>>(rel, RELP);
  T(f1_w1, f1_w1t, 512, 2048);  T(f1_w2, f1_w2t, 2048, 512);
  T(wq, wqt, 512, 512);         T(wkv, wkvt, 512, 1024);
  T(wo, wot, 512, 512);         T(cw1, cw1t, 512, 2048);
  T(cw2, cw2t, 1024, 512);      T(f2_w1, f2_w1t, 512, 2048);
  T(f2_w2, f2_w2t, 2048, 512);

  // ---- FF1 half-step ----
  ln_kernel<false><<<8192, 256, 0, stream>>>(X, f1_g, f1_b, H);
  { GemmArgs g = GA(H, f1_w1t, f1_b1, MID, nullptr, nullptr, 512, 512, 512, 2048, 1.f, 0.f);
    gemm_bt<128, 128, 2, 2, 1><<<dim3(16, 64, 1), 256, 0, stream>>>(g); }
  { GemmArgs g = GA(MID, f1_w2t, f1_b2, nullptr, X, nullptr, 2048, 2048, 2048, 512, 1.f, 0.5f);
    gemm_bt<64, 128, 1, 4, 2><<<dim3(4, 128, 1), 256, 0, stream>>>(g); }

  // ---- attention ----
  ln_kernel<false><<<8192, 256, 0, stream>>>(X, a_g, a_b, H);
  { GemmArgs g = GA(H, wqt, nullptr, Q, nullptr, nullptr, 512, 512, 512, 512, 0.125f, 0.f);
    gemm_bt<128, 128, 2, 2, 0><<<dim3(4, 64, 1), 256, 0, stream>>>(g); }   // q (scale folded)
  { GemmArgs g = GA(H, wkvt, nullptr, KV, nullptr, nullptr, 512, 512, 512, 1024, 1.f, 0.f);
    gemm_bt<128, 128, 2, 2, 0><<<dim3(8, 64, 1), 256, 0, stream>>>(g); }   // k|v
  vt_kernel<<<dim3(16, 64), 256, 0, stream>>>(KV, VT);

  // fused: T=q@rel^T (in-LDS), S = qk^T + bias, softmax, O = P @ V
  attn_kernel<<<dim3(32, 64), 512, 0, stream>>>(Q, KV, VT, RELP, O);

  { GemmArgs g = GA(O, wot, wo_b, nullptr, X, nullptr, 512, 512, 512, 512, 1.f, 1.f);
    gemm_bt<64, 128, 1, 4, 2><<<dim3(4, 128, 1), 256, 0, stream>>>(g); }   // x += o@wo + b

  // ---- conv module ----
  ln_kernel<false><<<8192, 256, 0, stream>>>(X, c_g, c_b, H);
  { GemmArgs g = GA(H, cw1t, cb1, MID, nullptr, nullptr, 512, 512, 512, 2048, 1.f, 0.f);
    gemm_bt<128, 128, 2, 2, 0><<<dim3(16, 64, 1), 256, 0, stream>>>(g); }  // pw1 + bias
  glu_kernel<<<4096, 256, 0, stream>>>(MID, GLU);
  dwconv_kernel<<<dim3(32, 16, 8), 256, 0, stream>>>(GLU, dwp, dbp, bn_g, bn_b, bn_m, bn_v, DWO);
  { GemmArgs g = GA(DWO, cw2t, cb2, nullptr, X, nullptr, 1024, 1024, 1024, 512, 1.f, 1.f);
    gemm_bt<64, 128, 1, 4, 2><<<dim3(4, 128, 1), 256, 0, stream>>>(g); }   // x += h@cw2 + b

  // ---- FF2 half-step + post-LN (f32 out) ----
  ln_kernel<false><<<8192, 256, 0, stream>>>(X, f2_g, f2_b, H);
  { GemmArgs g = GA(H, f2_w1t, f2_b1, MID, nullptr, nullptr, 512, 512, 512, 2048, 1.f, 0.f);
    gemm_bt<128, 128, 2, 2, 1><<<dim3(16, 64, 1), 256, 0, stream>>>(g); }
  { GemmArgs g = GA(MID, f2_w2t, f2_b2, nullptr, X, nullptr, 2048, 2048, 2048, 512, 1.f, 0.5f);
    gemm_bt<64, 128, 1, 4, 2><<<dim3(4, 128, 1), 256, 0, stream>>>(g); }
  ln_kernel<true><<<8192, 256, 0, stream>>>(X, p_g, p_b, (float*)d_out);
}